// Round 1
// baseline (1923.706 us; speedup 1.0000x reference)
//
#include <hip/hip_runtime.h>
#include <math.h>

// ---------------------------------------------------------------------------
// InvKin: 3x(Linear+BN(train)+ReLU) -> Linear(3) -> DH forward kinematics.
// Multi-pass because BN uses full-batch statistics:
//   P0  memset stats region of ws
//   P1  k_stats_x : Sx[3], Sxx[6] over x            (layer-1 stats are analytic)
//   P2  k_fin1    : fold BN1 into W1p/c1
//   P3  k_stats2  : per-row h1, accumulate sum/ssq of z2 = W2 h1 + b2
//   P4  k_fin_dense: fold BN2 into W2p/c2
//   P5  k_stats3  : per-row h1,h2, accumulate stats of z3
//   P6  k_fin_dense: fold BN3 into W3p/c3
//   P7  k_final   : per-row h1,h2,h3, thetas, closed-form FK, write outputs
// Row-per-lane GEMMs: weights are wave-uniform -> scalar loads; VALU does FMAs.
// ---------------------------------------------------------------------------

#define WS_STAT9   0      // 9 floats: Sx0..2, Sxx00,01,02,11,12,22
#define WS_SUM2    16
#define WS_SSQ2    80
#define WS_SUM3    144
#define WS_SSQ3    208
#define WS_W1P     288    // 192 floats (BN-folded W1)
#define WS_C1      480    // 64
#define WS_W2P     544    // 4096
#define WS_C2      4640   // 64
#define WS_W3P     4704   // 4096
#define WS_C3      8800   // 64  -> total 8864 floats (~35 KB)

static constexpr float kEps = 1e-5f;

__device__ __forceinline__ float wred64(float v) {
  v += __shfl_xor(v, 32, 64);
  v += __shfl_xor(v, 16, 64);
  v += __shfl_xor(v, 8, 64);
  v += __shfl_xor(v, 4, 64);
  v += __shfl_xor(v, 2, 64);
  v += __shfl_xor(v, 1, 64);
  return v;
}

// ---- P1: second-moment stats of x ----------------------------------------
__global__ void __launch_bounds__(256) k_stats_x(const float* __restrict__ x,
                                                 float* __restrict__ ws, int B) {
  int tid = blockIdx.x * 256 + threadIdx.x;
  int nt = gridDim.x * 256;
  float s0 = 0.f, s1 = 0.f, s2 = 0.f;
  float q00 = 0.f, q01 = 0.f, q02 = 0.f, q11 = 0.f, q12 = 0.f, q22 = 0.f;
  for (int r = tid; r < B; r += nt) {
    float x0 = x[3 * r], x1 = x[3 * r + 1], x2 = x[3 * r + 2];
    s0 += x0; s1 += x1; s2 += x2;
    q00 = fmaf(x0, x0, q00); q01 = fmaf(x0, x1, q01); q02 = fmaf(x0, x2, q02);
    q11 = fmaf(x1, x1, q11); q12 = fmaf(x1, x2, q12); q22 = fmaf(x2, x2, q22);
  }
  s0 = wred64(s0); s1 = wred64(s1); s2 = wred64(s2);
  q00 = wred64(q00); q01 = wred64(q01); q02 = wred64(q02);
  q11 = wred64(q11); q12 = wred64(q12); q22 = wred64(q22);
  __shared__ float part[9];
  if (threadIdx.x < 9) part[threadIdx.x] = 0.f;
  __syncthreads();
  if ((threadIdx.x & 63) == 0) {
    atomicAdd(&part[0], s0); atomicAdd(&part[1], s1); atomicAdd(&part[2], s2);
    atomicAdd(&part[3], q00); atomicAdd(&part[4], q01); atomicAdd(&part[5], q02);
    atomicAdd(&part[6], q11); atomicAdd(&part[7], q12); atomicAdd(&part[8], q22);
  }
  __syncthreads();
  if (threadIdx.x < 9) atomicAdd(&ws[WS_STAT9 + threadIdx.x], part[threadIdx.x]);
}

// ---- P2: finalize layer-1 BN fold (analytic mean/var from x moments) -----
__global__ void k_fin1(const float* __restrict__ W1, const float* __restrict__ b1,
                       const float* __restrict__ g1, const float* __restrict__ be1,
                       float* __restrict__ ws, int B) {
  int j = threadIdx.x;  // 64 threads
  float inv = 1.0f / (float)B;
  float ex0 = ws[0] * inv, ex1 = ws[1] * inv, ex2 = ws[2] * inv;
  float c00 = ws[3] * inv - ex0 * ex0;
  float c01 = ws[4] * inv - ex0 * ex1;
  float c02 = ws[5] * inv - ex0 * ex2;
  float c11 = ws[6] * inv - ex1 * ex1;
  float c12 = ws[7] * inv - ex1 * ex2;
  float c22 = ws[8] * inv - ex2 * ex2;
  float w0 = W1[3 * j], w1 = W1[3 * j + 1], w2 = W1[3 * j + 2];
  float mean = w0 * ex0 + w1 * ex1 + w2 * ex2 + b1[j];
  float var = w0 * w0 * c00 + w1 * w1 * c11 + w2 * w2 * c22 +
              2.f * (w0 * w1 * c01 + w0 * w2 * c02 + w1 * w2 * c12);
  float s = g1[j] * rsqrtf(var + kEps);
  ws[WS_W1P + 3 * j + 0] = s * w0;
  ws[WS_W1P + 3 * j + 1] = s * w1;
  ws[WS_W1P + 3 * j + 2] = s * w2;
  ws[WS_C1 + j] = fmaf(s, b1[j] - mean, be1[j]);
}

// ---- shared device helpers -----------------------------------------------
__device__ __forceinline__ void layer1_eval(const float* __restrict__ W1p,
                                            const float* __restrict__ c1,
                                            float x0, float x1, float x2,
                                            float h[64]) {
#pragma unroll
  for (int j = 0; j < 64; ++j) {
    float z = fmaf(W1p[3 * j + 2], x2,
               fmaf(W1p[3 * j + 1], x1, fmaf(W1p[3 * j], x0, c1[j])));
    h[j] = fmaxf(z, 0.f);
  }
}

__device__ __forceinline__ void dense_relu(const float* __restrict__ Wp,
                                           const float* __restrict__ c,
                                           const float hin[64], float hout[64]) {
#pragma unroll
  for (int j = 0; j < 64; ++j) {
    float a0 = 0.f, a1 = 0.f, a2 = 0.f, a3 = 0.f;
    const float* wr = Wp + j * 64;
#pragma unroll
    for (int k = 0; k < 64; k += 4) {
      a0 = fmaf(wr[k + 0], hin[k + 0], a0);
      a1 = fmaf(wr[k + 1], hin[k + 1], a1);
      a2 = fmaf(wr[k + 2], hin[k + 2], a2);
      a3 = fmaf(wr[k + 3], hin[k + 3], a3);
    }
    hout[j] = fmaxf((a0 + a1) + (a2 + a3) + c[j], 0.f);
  }
}

// accumulate per-unit sum/sumsq of raw z = W hin + b across rows (1 row/lane)
__device__ __forceinline__ void dense_stats(const float* __restrict__ W,
                                            const float* __restrict__ b,
                                            const float hin[64], int lane,
                                            float valid, float& accS, float& accQ) {
#pragma unroll 1
  for (int j = 0; j < 64; ++j) {
    float a0 = 0.f, a1 = 0.f, a2 = 0.f, a3 = 0.f;
    const float* wr = W + j * 64;
#pragma unroll
    for (int k = 0; k < 64; k += 4) {
      a0 = fmaf(wr[k + 0], hin[k + 0], a0);
      a1 = fmaf(wr[k + 1], hin[k + 1], a1);
      a2 = fmaf(wr[k + 2], hin[k + 2], a2);
      a3 = fmaf(wr[k + 3], hin[k + 3], a3);
    }
    float z = (((a0 + a1) + (a2 + a3)) + b[j]) * valid;
    float zz = z * z;
    float rs = wred64(z);
    float rq = wred64(zz);
    accS += (lane == j) ? rs : 0.f;
    accQ += (lane == j) ? rq : 0.f;
  }
}

__device__ __forceinline__ void block_combine_stats(float accS, float accQ,
                                                    float* __restrict__ sumg,
                                                    float* __restrict__ ssqg) {
  __shared__ float sS[256], sQ[256];
  sS[threadIdx.x] = accS;
  sQ[threadIdx.x] = accQ;
  __syncthreads();
  if (threadIdx.x < 64) {
    float S = sS[threadIdx.x] + sS[threadIdx.x + 64] + sS[threadIdx.x + 128] + sS[threadIdx.x + 192];
    float Q = sQ[threadIdx.x] + sQ[threadIdx.x + 64] + sQ[threadIdx.x + 128] + sQ[threadIdx.x + 192];
    atomicAdd(&sumg[threadIdx.x], S);
    atomicAdd(&ssqg[threadIdx.x], Q);
  }
}

// ---- P3: stats of z2 ------------------------------------------------------
__global__ void __launch_bounds__(256) k_stats2(const float* __restrict__ x,
                                                const float* __restrict__ W2,
                                                const float* __restrict__ b2,
                                                float* __restrict__ ws, int B) {
  const float* W1p = ws + WS_W1P;
  const float* c1 = ws + WS_C1;
  int tid = blockIdx.x * 256 + threadIdx.x;
  int nt = gridDim.x * 256;
  int lane = threadIdx.x & 63;
  float accS = 0.f, accQ = 0.f;
  int iters = (B + nt - 1) / nt;
  for (int it = 0; it < iters; ++it) {
    int r = tid + it * nt;
    float valid = (r < B) ? 1.f : 0.f;
    int rc = (r < B) ? r : (B - 1);
    float x0 = x[3 * rc], x1 = x[3 * rc + 1], x2 = x[3 * rc + 2];
    float h1[64];
    layer1_eval(W1p, c1, x0, x1, x2, h1);
    dense_stats(W2, b2, h1, lane, valid, accS, accQ);
  }
  block_combine_stats(accS, accQ, ws + WS_SUM2, ws + WS_SSQ2);
}

// ---- P4/P6: finalize a dense BN fold -------------------------------------
__global__ void k_fin_dense(const float* __restrict__ W, const float* __restrict__ b,
                            const float* __restrict__ g, const float* __restrict__ be,
                            const float* __restrict__ sum, const float* __restrict__ ssq,
                            float* __restrict__ Wp, float* __restrict__ cc, int B) {
  int j = threadIdx.x;  // 64 threads
  float inv = 1.0f / (float)B;
  float mean = sum[j] * inv;
  float var = ssq[j] * inv - mean * mean;
  float s = g[j] * rsqrtf(var + kEps);
  for (int k = 0; k < 64; ++k) Wp[j * 64 + k] = s * W[j * 64 + k];
  cc[j] = fmaf(s, b[j] - mean, be[j]);
}

// ---- P5: stats of z3 ------------------------------------------------------
__global__ void __launch_bounds__(256) k_stats3(const float* __restrict__ x,
                                                const float* __restrict__ W3,
                                                const float* __restrict__ b3,
                                                float* __restrict__ ws, int B) {
  const float* W1p = ws + WS_W1P;
  const float* c1 = ws + WS_C1;
  const float* W2p = ws + WS_W2P;
  const float* c2 = ws + WS_C2;
  int tid = blockIdx.x * 256 + threadIdx.x;
  int nt = gridDim.x * 256;
  int lane = threadIdx.x & 63;
  float accS = 0.f, accQ = 0.f;
  int iters = (B + nt - 1) / nt;
  for (int it = 0; it < iters; ++it) {
    int r = tid + it * nt;
    float valid = (r < B) ? 1.f : 0.f;
    int rc = (r < B) ? r : (B - 1);
    float x0 = x[3 * rc], x1 = x[3 * rc + 1], x2 = x[3 * rc + 2];
    float h1[64], h2[64];
    layer1_eval(W1p, c1, x0, x1, x2, h1);
    dense_relu(W2p, c2, h1, h2);
    dense_stats(W3, b3, h2, lane, valid, accS, accQ);
  }
  block_combine_stats(accS, accQ, ws + WS_SUM3, ws + WS_SSQ3);
}

// ---- P7: final forward + DH forward kinematics ---------------------------
__global__ void __launch_bounds__(256) k_final(const float* __restrict__ x,
                                               const float* __restrict__ W4,
                                               const float* __restrict__ b4,
                                               const float* __restrict__ ws,
                                               float* __restrict__ out, int B) {
  const float* W1p = ws + WS_W1P;
  const float* c1 = ws + WS_C1;
  const float* W2p = ws + WS_W2P;
  const float* c2 = ws + WS_C2;
  const float* W3p = ws + WS_W3P;
  const float* c3 = ws + WS_C3;
  int tid = blockIdx.x * 256 + threadIdx.x;
  int nt = gridDim.x * 256;
  for (int r = tid; r < B; r += nt) {
    float x0 = x[3 * r], x1 = x[3 * r + 1], x2 = x[3 * r + 2];
    float h1[64], h2[64];
    layer1_eval(W1p, c1, x0, x1, x2, h1);
    dense_relu(W2p, c2, h1, h2);
    float t0 = b4[0], t1 = b4[1], t2 = b4[2];
    // layer3 rolled; h3[j] consumed immediately by the 3-unit head
#pragma unroll 1
    for (int j = 0; j < 64; ++j) {
      float a0 = 0.f, a1 = 0.f, a2 = 0.f, a3 = 0.f;
      const float* wr = W3p + j * 64;
#pragma unroll
      for (int k = 0; k < 64; k += 4) {
        a0 = fmaf(wr[k + 0], h2[k + 0], a0);
        a1 = fmaf(wr[k + 1], h2[k + 1], a1);
        a2 = fmaf(wr[k + 2], h2[k + 2], a2);
        a3 = fmaf(wr[k + 3], h2[k + 3], a3);
      }
      float h3 = fmaxf((a0 + a1) + (a2 + a3) + c3[j], 0.f);
      t0 = fmaf(W4[j], h3, t0);
      t1 = fmaf(W4[64 + j], h3, t1);
      t2 = fmaf(W4[128 + j], h3, t2);
    }
    out[3 * r + 0] = t0;
    out[3 * r + 1] = t1;
    out[3 * r + 2] = t2;
    // FK closed form: A1(theta0, alpha=pi/2) * A2(theta1, r=.12) * A3(theta2, r=.115)
    float s0, c0v, s1, c1v, s12, c12;
    sincosf(t0, &s0, &c0v);
    sincosf(t1, &s1, &c1v);
    sincosf(t1 + t2, &s12, &c12);
    float A = fmaf(0.115f, c12, 0.12f * c1v);
    int o2 = 3 * B + 3 * r;
    out[o2 + 0] = c0v * A;
    out[o2 + 1] = s0 * A;
    out[o2 + 2] = fmaf(0.115f, s12, 0.12f * s1);
  }
}

extern "C" void kernel_launch(void* const* d_in, const int* in_sizes, int n_in,
                              void* d_out, int out_size, void* d_ws, size_t ws_size,
                              hipStream_t stream) {
  const float* x = (const float*)d_in[0];
  const float* W1 = (const float*)d_in[1];
  const float* b1 = (const float*)d_in[2];
  const float* g1 = (const float*)d_in[3];
  const float* be1 = (const float*)d_in[4];
  const float* W2 = (const float*)d_in[5];
  const float* b2 = (const float*)d_in[6];
  const float* g2 = (const float*)d_in[7];
  const float* be2 = (const float*)d_in[8];
  const float* W3 = (const float*)d_in[9];
  const float* b3 = (const float*)d_in[10];
  const float* g3 = (const float*)d_in[11];
  const float* be3 = (const float*)d_in[12];
  const float* W4 = (const float*)d_in[13];
  const float* b4 = (const float*)d_in[14];
  float* ws = (float*)d_ws;
  float* out = (float*)d_out;
  int B = in_sizes[0] / 3;

  // zero the accumulation region (stat9 + sum/ssq for layers 2,3)
  hipMemsetAsync(d_ws, 0, 272 * sizeof(float), stream);

  const int blocks = 1024, thr = 256;
  k_stats_x<<<blocks, thr, 0, stream>>>(x, ws, B);
  k_fin1<<<1, 64, 0, stream>>>(W1, b1, g1, be1, ws, B);
  k_stats2<<<blocks, thr, 0, stream>>>(x, W2, b2, ws, B);
  k_fin_dense<<<1, 64, 0, stream>>>(W2, b2, g2, be2, ws + WS_SUM2, ws + WS_SSQ2,
                                    ws + WS_W2P, ws + WS_C2, B);
  k_stats3<<<blocks, thr, 0, stream>>>(x, W3, b3, ws, B);
  k_fin_dense<<<1, 64, 0, stream>>>(W3, b3, g3, be3, ws + WS_SUM3, ws + WS_SSQ3,
                                    ws + WS_W3P, ws + WS_C3, B);
  k_final<<<blocks, thr, 0, stream>>>(x, W4, b4, ws, out, B);
}

// Round 5
// 1043.929 us; speedup vs baseline: 1.8428x; 1.8428x over previous
//
#include <hip/hip_runtime.h>
#include <math.h>

// ---------------------------------------------------------------------------
// InvKin, fp32-VALU pipeline with bf16 z-materialization (R4).
// MFMA attempts R1-R3 failed structurally; this round returns to the R1 math
// (which PASSED) and removes its measured bottleneck: the per-row per-unit
// cross-lane reductions (768 ds_swizzle ops/row -> VALUBusy 38%).
//
// Fast path (ws_size >= 64 KiB + B*128 bytes):
//   P1 k_stats_x : x second moments (layer-1 BN stats are analytic)
//   P2 k_fin1    : fold BN1 -> fp32 W1p[64][3] + c1[64]
//   P3 k_z2      : per-row h1 -> raw z2 = W2 h1 + b2 -> bf16 zbuf[B][64]
//   P4 k_colstats: coalesced per-unit sum/ssq of zbuf  (unit = tid&63)
//   P5 k_fin_bn  : s2 = g2*rsqrt(var+eps), c2 = be2 - s2*mean2
//   P6 k_z3      : read z2 row, h2 = relu(s2*z2+c2), z3 = W3 h2 + b3,
//                  write z3 IN PLACE over z2 (row read fully before write)
//   P7 k_colstats: stats of z3
//   P8 k_fin_bn  : s3, c3
//   P9 k_final   : read z3 row, h3, head, closed-form FK, write outputs
// No work is duplicated: L1+L2 once, L3 once, head once (minimal FLOPs).
// Stats passes are pure coalesced HBM streams with 2 private accumulators.
//
// Fallback path (small ws): the exact R1 kernel set (verified PASS).
// ---------------------------------------------------------------------------

static constexpr float kEps = 1e-5f;

// shared ws fp32 indices (both paths)
#define WS_STAT9 0
#define WS_SUM2  16
#define WS_SSQ2  80
#define WS_SUM3  144
#define WS_SSQ3  208
#define WS_W1P   288    // [64][3] fp32 (BN1-folded)
#define WS_C1    480    // [64]
// fast path only
#define FP_S2    8192
#define FP_C2    8256
#define FP_S3    8320
#define FP_C3    8384
// fallback (R1) only — may overlap FP_* since only one path ever runs
#define RC_W2P   544
#define RC_C2    4640
#define RC_W3P   4704
#define RC_C3    8800
// z buffer: byte offset 65536 (ushort index 32768)
#define ZB_U16   32768

__device__ __forceinline__ unsigned short f2bf(float f) {
  unsigned u = __builtin_bit_cast(unsigned, f);
  u += 0x7fffu + ((u >> 16) & 1u);
  return (unsigned short)(u >> 16);
}
__device__ __forceinline__ unsigned packbf2(float a, float b) {
  return (unsigned)f2bf(a) | ((unsigned)f2bf(b) << 16);
}
__device__ __forceinline__ float bfbits(unsigned short s) {
  unsigned u = ((unsigned)s) << 16;
  return __builtin_bit_cast(float, u);
}
__device__ __forceinline__ void unpack2(unsigned w, float& lo, float& hi) {
  lo = __builtin_bit_cast(float, w << 16);
  hi = __builtin_bit_cast(float, w & 0xffff0000u);
}

__device__ __forceinline__ float wred64(float v) {
  v += __shfl_xor(v, 32, 64);
  v += __shfl_xor(v, 16, 64);
  v += __shfl_xor(v, 8, 64);
  v += __shfl_xor(v, 4, 64);
  v += __shfl_xor(v, 2, 64);
  v += __shfl_xor(v, 1, 64);
  return v;
}

// ---- shared device helpers (verified in R1) ------------------------------
__device__ __forceinline__ void layer1_eval(const float* __restrict__ W1p,
                                            const float* __restrict__ c1,
                                            float x0, float x1, float x2,
                                            float h[64]) {
#pragma unroll
  for (int j = 0; j < 64; ++j) {
    float z = fmaf(W1p[3 * j + 2], x2,
               fmaf(W1p[3 * j + 1], x1, fmaf(W1p[3 * j], x0, c1[j])));
    h[j] = fmaxf(z, 0.f);
  }
}

__device__ __forceinline__ float dot64(const float* __restrict__ wr,
                                       const float hin[64]) {
  float a0 = 0.f, a1 = 0.f, a2 = 0.f, a3 = 0.f;
#pragma unroll
  for (int k = 0; k < 64; k += 4) {
    a0 = fmaf(wr[k + 0], hin[k + 0], a0);
    a1 = fmaf(wr[k + 1], hin[k + 1], a1);
    a2 = fmaf(wr[k + 2], hin[k + 2], a2);
    a3 = fmaf(wr[k + 3], hin[k + 3], a3);
  }
  return (a0 + a1) + (a2 + a3);
}

// ---- P1: x second moments (shared) ---------------------------------------
__global__ void __launch_bounds__(256) k_stats_x(const float* __restrict__ x,
                                                 float* __restrict__ ws, int B) {
  int tid = blockIdx.x * 256 + threadIdx.x;
  int nt = gridDim.x * 256;
  float s0 = 0.f, s1 = 0.f, s2 = 0.f;
  float q00 = 0.f, q01 = 0.f, q02 = 0.f, q11 = 0.f, q12 = 0.f, q22 = 0.f;
  for (int r = tid; r < B; r += nt) {
    float x0 = x[3 * r], x1 = x[3 * r + 1], x2 = x[3 * r + 2];
    s0 += x0; s1 += x1; s2 += x2;
    q00 = fmaf(x0, x0, q00); q01 = fmaf(x0, x1, q01); q02 = fmaf(x0, x2, q02);
    q11 = fmaf(x1, x1, q11); q12 = fmaf(x1, x2, q12); q22 = fmaf(x2, x2, q22);
  }
  s0 = wred64(s0); s1 = wred64(s1); s2 = wred64(s2);
  q00 = wred64(q00); q01 = wred64(q01); q02 = wred64(q02);
  q11 = wred64(q11); q12 = wred64(q12); q22 = wred64(q22);
  __shared__ float part[9];
  if (threadIdx.x < 9) part[threadIdx.x] = 0.f;
  __syncthreads();
  if ((threadIdx.x & 63) == 0) {
    atomicAdd(&part[0], s0); atomicAdd(&part[1], s1); atomicAdd(&part[2], s2);
    atomicAdd(&part[3], q00); atomicAdd(&part[4], q01); atomicAdd(&part[5], q02);
    atomicAdd(&part[6], q11); atomicAdd(&part[7], q12); atomicAdd(&part[8], q22);
  }
  __syncthreads();
  if (threadIdx.x < 9) atomicAdd(&ws[WS_STAT9 + threadIdx.x], part[threadIdx.x]);
}

// ---- P2: fold BN1 (shared) ------------------------------------------------
__global__ void k_fin1(const float* __restrict__ W1, const float* __restrict__ b1,
                       const float* __restrict__ g1, const float* __restrict__ be1,
                       float* __restrict__ ws, int B) {
  int j = threadIdx.x;  // 64
  float inv = 1.0f / (float)B;
  float ex0 = ws[0] * inv, ex1 = ws[1] * inv, ex2 = ws[2] * inv;
  float c00 = ws[3] * inv - ex0 * ex0;
  float c01 = ws[4] * inv - ex0 * ex1;
  float c02 = ws[5] * inv - ex0 * ex2;
  float c11 = ws[6] * inv - ex1 * ex1;
  float c12 = ws[7] * inv - ex1 * ex2;
  float c22 = ws[8] * inv - ex2 * ex2;
  float w0 = W1[3 * j], w1 = W1[3 * j + 1], w2 = W1[3 * j + 2];
  float mean = w0 * ex0 + w1 * ex1 + w2 * ex2 + b1[j];
  float var = w0 * w0 * c00 + w1 * w1 * c11 + w2 * w2 * c22 +
              2.f * (w0 * w1 * c01 + w0 * w2 * c02 + w1 * w2 * c12);
  float s = g1[j] * rsqrtf(var + kEps);
  ws[WS_W1P + 3 * j + 0] = s * w0;
  ws[WS_W1P + 3 * j + 1] = s * w1;
  ws[WS_W1P + 3 * j + 2] = s * w2;
  ws[WS_C1 + j] = fmaf(s, b1[j] - mean, be1[j]);
}

// =========================== FAST PATH =====================================

// ---- P3: z2 = W2 h1 + b2 -> bf16 zbuf ------------------------------------
__global__ void __launch_bounds__(256) k_z2(const float* __restrict__ x,
                                            const float* __restrict__ W2,
                                            const float* __restrict__ b2,
                                            const float* __restrict__ ws,
                                            unsigned short* __restrict__ zb, int B) {
  const float* W1p = ws + WS_W1P;
  const float* c1 = ws + WS_C1;
  int tid = blockIdx.x * 256 + threadIdx.x;
  int nt = gridDim.x * 256;
  for (int r = tid; r < B; r += nt) {
    float x0 = x[3 * r], x1 = x[3 * r + 1], x2 = x[3 * r + 2];
    float h1[64];
    layer1_eval(W1p, c1, x0, x1, x2, h1);
    uint4* zrow = (uint4*)(zb + (size_t)r * 64);
#pragma unroll 1
    for (int jb = 0; jb < 8; ++jb) {
      float z[8];
#pragma unroll
      for (int u = 0; u < 8; ++u) {
        int j = jb * 8 + u;
        z[u] = dot64(W2 + j * 64, h1) + b2[j];
      }
      uint4 v;
      v.x = packbf2(z[0], z[1]);
      v.y = packbf2(z[2], z[3]);
      v.z = packbf2(z[4], z[5]);
      v.w = packbf2(z[6], z[7]);
      zrow[jb] = v;
    }
  }
}

// ---- P4/P7: coalesced per-unit sum/ssq of zbuf ---------------------------
__global__ void __launch_bounds__(256) k_colstats(const unsigned short* __restrict__ zb,
                                                  float* __restrict__ sumg,
                                                  float* __restrict__ ssqg, int B) {
  int u = threadIdx.x & 63;
  int rloc = threadIdx.x >> 6;              // 0..3
  int rstep = gridDim.x * 4;
  float accS = 0.f, accQ = 0.f;
  for (int r = blockIdx.x * 4 + rloc; r < B; r += rstep) {
    float z = bfbits(zb[(size_t)r * 64 + u]);
    accS += z;
    accQ = fmaf(z, z, accQ);
  }
  __shared__ float sS[64], sQ[64];
  if (threadIdx.x < 64) { sS[threadIdx.x] = 0.f; sQ[threadIdx.x] = 0.f; }
  __syncthreads();
  atomicAdd(&sS[u], accS);
  atomicAdd(&sQ[u], accQ);
  __syncthreads();
  if (threadIdx.x < 64) {
    atomicAdd(&sumg[threadIdx.x], sS[threadIdx.x]);
    atomicAdd(&ssqg[threadIdx.x], sQ[threadIdx.x]);
  }
}

// ---- P5/P8: BN scale/shift only ------------------------------------------
__global__ void k_fin_bn(const float* __restrict__ sum, const float* __restrict__ ssq,
                         const float* __restrict__ g, const float* __restrict__ be,
                         float* __restrict__ sOut, float* __restrict__ cOut, int B) {
  int j = threadIdx.x;  // 64
  float inv = 1.0f / (float)B;
  float mean = sum[j] * inv;
  float var = ssq[j] * inv - mean * mean;
  float s = g[j] * rsqrtf(var + kEps);
  sOut[j] = s;
  cOut[j] = fmaf(-s, mean, be[j]);
}

// ---- P6: z3 = W3 relu(s2*z2+c2) + b3, in place ---------------------------
__global__ void __launch_bounds__(256) k_z3(const float* __restrict__ W3,
                                            const float* __restrict__ b3,
                                            const float* __restrict__ ws,
                                            unsigned short* __restrict__ zb, int B) {
  const float* s2 = ws + FP_S2;
  const float* c2 = ws + FP_C2;
  int tid = blockIdx.x * 256 + threadIdx.x;
  int nt = gridDim.x * 256;
  for (int r = tid; r < B; r += nt) {
    uint4* zrow = (uint4*)(zb + (size_t)r * 64);
    float h2[64];
#pragma unroll
    for (int jb = 0; jb < 8; ++jb) {
      uint4 v = zrow[jb];
      float z0, z1, z2v, z3v, z4, z5, z6, z7;
      unpack2(v.x, z0, z1); unpack2(v.y, z2v, z3v);
      unpack2(v.z, z4, z5); unpack2(v.w, z6, z7);
      int k = jb * 8;
      h2[k + 0] = fmaxf(fmaf(s2[k + 0], z0, c2[k + 0]), 0.f);
      h2[k + 1] = fmaxf(fmaf(s2[k + 1], z1, c2[k + 1]), 0.f);
      h2[k + 2] = fmaxf(fmaf(s2[k + 2], z2v, c2[k + 2]), 0.f);
      h2[k + 3] = fmaxf(fmaf(s2[k + 3], z3v, c2[k + 3]), 0.f);
      h2[k + 4] = fmaxf(fmaf(s2[k + 4], z4, c2[k + 4]), 0.f);
      h2[k + 5] = fmaxf(fmaf(s2[k + 5], z5, c2[k + 5]), 0.f);
      h2[k + 6] = fmaxf(fmaf(s2[k + 6], z6, c2[k + 6]), 0.f);
      h2[k + 7] = fmaxf(fmaf(s2[k + 7], z7, c2[k + 7]), 0.f);
    }
#pragma unroll 1
    for (int jb = 0; jb < 8; ++jb) {
      float z[8];
#pragma unroll
      for (int u = 0; u < 8; ++u) {
        int j = jb * 8 + u;
        z[u] = dot64(W3 + j * 64, h2) + b3[j];
      }
      uint4 v;
      v.x = packbf2(z[0], z[1]);
      v.y = packbf2(z[2], z[3]);
      v.z = packbf2(z[4], z[5]);
      v.w = packbf2(z[6], z[7]);
      zrow[jb] = v;
    }
  }
}

// ---- P9: h3 -> head -> FK -> out ------------------------------------------
__global__ void __launch_bounds__(256) k_final_fast(const unsigned short* __restrict__ zb,
                                                    const float* __restrict__ W4,
                                                    const float* __restrict__ b4,
                                                    const float* __restrict__ ws,
                                                    float* __restrict__ out, int B) {
  const float* s3 = ws + FP_S3;
  const float* c3 = ws + FP_C3;
  int tid = blockIdx.x * 256 + threadIdx.x;
  int nt = gridDim.x * 256;
  for (int r = tid; r < B; r += nt) {
    const uint4* zrow = (const uint4*)(zb + (size_t)r * 64);
    float h3[64];
#pragma unroll
    for (int jb = 0; jb < 8; ++jb) {
      uint4 v = zrow[jb];
      float z0, z1, z2v, z3v, z4, z5, z6, z7;
      unpack2(v.x, z0, z1); unpack2(v.y, z2v, z3v);
      unpack2(v.z, z4, z5); unpack2(v.w, z6, z7);
      int k = jb * 8;
      h3[k + 0] = fmaxf(fmaf(s3[k + 0], z0, c3[k + 0]), 0.f);
      h3[k + 1] = fmaxf(fmaf(s3[k + 1], z1, c3[k + 1]), 0.f);
      h3[k + 2] = fmaxf(fmaf(s3[k + 2], z2v, c3[k + 2]), 0.f);
      h3[k + 3] = fmaxf(fmaf(s3[k + 3], z3v, c3[k + 3]), 0.f);
      h3[k + 4] = fmaxf(fmaf(s3[k + 4], z4, c3[k + 4]), 0.f);
      h3[k + 5] = fmaxf(fmaf(s3[k + 5], z5, c3[k + 5]), 0.f);
      h3[k + 6] = fmaxf(fmaf(s3[k + 6], z6, c3[k + 6]), 0.f);
      h3[k + 7] = fmaxf(fmaf(s3[k + 7], z7, c3[k + 7]), 0.f);
    }
    float t0 = b4[0] + dot64(W4, h3);
    float t1 = b4[1] + dot64(W4 + 64, h3);
    float t2 = b4[2] + dot64(W4 + 128, h3);
    out[3 * r + 0] = t0;
    out[3 * r + 1] = t1;
    out[3 * r + 2] = t2;
    float s0, c0v, s1, c1v, s12, c12;
    sincosf(t0, &s0, &c0v);
    sincosf(t1, &s1, &c1v);
    sincosf(t1 + t2, &s12, &c12);
    float A = fmaf(0.115f, c12, 0.12f * c1v);
    size_t o2 = (size_t)3 * B + 3 * r;
    out[o2 + 0] = c0v * A;
    out[o2 + 1] = s0 * A;
    out[o2 + 2] = fmaf(0.115f, s12, 0.12f * s1);
  }
}

// ========================= FALLBACK (R1, verified) =========================

__device__ __forceinline__ void dense_relu_rc(const float* __restrict__ Wp,
                                              const float* __restrict__ c,
                                              const float hin[64], float hout[64]) {
#pragma unroll
  for (int j = 0; j < 64; ++j)
    hout[j] = fmaxf(dot64(Wp + j * 64, hin) + c[j], 0.f);
}

__device__ __forceinline__ void dense_stats_rc(const float* __restrict__ W,
                                               const float* __restrict__ b,
                                               const float hin[64], int lane,
                                               float valid, float& accS, float& accQ) {
#pragma unroll 1
  for (int j = 0; j < 64; ++j) {
    float z = (dot64(W + j * 64, hin) + b[j]) * valid;
    float rs = wred64(z);
    float rq = wred64(z * z);
    accS += (lane == j) ? rs : 0.f;
    accQ += (lane == j) ? rq : 0.f;
  }
}

__device__ __forceinline__ void block_combine_rc(float accS, float accQ,
                                                 float* __restrict__ sumg,
                                                 float* __restrict__ ssqg) {
  __shared__ float sS[256], sQ[256];
  sS[threadIdx.x] = accS;
  sQ[threadIdx.x] = accQ;
  __syncthreads();
  if (threadIdx.x < 64) {
    float S = sS[threadIdx.x] + sS[threadIdx.x + 64] + sS[threadIdx.x + 128] + sS[threadIdx.x + 192];
    float Q = sQ[threadIdx.x] + sQ[threadIdx.x + 64] + sQ[threadIdx.x + 128] + sQ[threadIdx.x + 192];
    atomicAdd(&sumg[threadIdx.x], S);
    atomicAdd(&ssqg[threadIdx.x], Q);
  }
}

__global__ void __launch_bounds__(256) k_stats2_rc(const float* __restrict__ x,
                                                   const float* __restrict__ W2,
                                                   const float* __restrict__ b2,
                                                   float* __restrict__ ws, int B) {
  const float* W1p = ws + WS_W1P;
  const float* c1 = ws + WS_C1;
  int tid = blockIdx.x * 256 + threadIdx.x;
  int nt = gridDim.x * 256;
  int lane = threadIdx.x & 63;
  float accS = 0.f, accQ = 0.f;
  int iters = (B + nt - 1) / nt;
  for (int it = 0; it < iters; ++it) {
    int r = tid + it * nt;
    float valid = (r < B) ? 1.f : 0.f;
    int rc = (r < B) ? r : (B - 1);
    float h1[64];
    layer1_eval(W1p, c1, x[3 * rc], x[3 * rc + 1], x[3 * rc + 2], h1);
    dense_stats_rc(W2, b2, h1, lane, valid, accS, accQ);
  }
  block_combine_rc(accS, accQ, ws + WS_SUM2, ws + WS_SSQ2);
}

__global__ void k_fin_dense_rc(const float* __restrict__ W, const float* __restrict__ b,
                               const float* __restrict__ g, const float* __restrict__ be,
                               const float* __restrict__ sum, const float* __restrict__ ssq,
                               float* __restrict__ Wp, float* __restrict__ cc, int B) {
  int j = threadIdx.x;
  float inv = 1.0f / (float)B;
  float mean = sum[j] * inv;
  float var = ssq[j] * inv - mean * mean;
  float s = g[j] * rsqrtf(var + kEps);
  for (int k = 0; k < 64; ++k) Wp[j * 64 + k] = s * W[j * 64 + k];
  cc[j] = fmaf(s, b[j] - mean, be[j]);
}

__global__ void __launch_bounds__(256) k_stats3_rc(const float* __restrict__ x,
                                                   const float* __restrict__ W3,
                                                   const float* __restrict__ b3,
                                                   float* __restrict__ ws, int B) {
  const float* W1p = ws + WS_W1P;
  const float* c1 = ws + WS_C1;
  const float* W2p = ws + RC_W2P;
  const float* c2 = ws + RC_C2;
  int tid = blockIdx.x * 256 + threadIdx.x;
  int nt = gridDim.x * 256;
  int lane = threadIdx.x & 63;
  float accS = 0.f, accQ = 0.f;
  int iters = (B + nt - 1) / nt;
  for (int it = 0; it < iters; ++it) {
    int r = tid + it * nt;
    float valid = (r < B) ? 1.f : 0.f;
    int rc = (r < B) ? r : (B - 1);
    float h1[64], h2[64];
    layer1_eval(W1p, c1, x[3 * rc], x[3 * rc + 1], x[3 * rc + 2], h1);
    dense_relu_rc(W2p, c2, h1, h2);
    dense_stats_rc(W3, b3, h2, lane, valid, accS, accQ);
  }
  block_combine_rc(accS, accQ, ws + WS_SUM3, ws + WS_SSQ3);
}

__global__ void __launch_bounds__(256) k_final_rc(const float* __restrict__ x,
                                                  const float* __restrict__ W4,
                                                  const float* __restrict__ b4,
                                                  const float* __restrict__ ws,
                                                  float* __restrict__ out, int B) {
  const float* W1p = ws + WS_W1P;
  const float* c1 = ws + WS_C1;
  const float* W2p = ws + RC_W2P;
  const float* c2 = ws + RC_C2;
  const float* W3p = ws + RC_W3P;
  const float* c3 = ws + RC_C3;
  int tid = blockIdx.x * 256 + threadIdx.x;
  int nt = gridDim.x * 256;
  for (int r = tid; r < B; r += nt) {
    float h1[64], h2[64];
    layer1_eval(W1p, c1, x[3 * r], x[3 * r + 1], x[3 * r + 2], h1);
    dense_relu_rc(W2p, c2, h1, h2);
    float t0 = b4[0], t1 = b4[1], t2 = b4[2];
#pragma unroll 1
    for (int j = 0; j < 64; ++j) {
      float h3 = fmaxf(dot64(W3p + j * 64, h2) + c3[j], 0.f);
      t0 = fmaf(W4[j], h3, t0);
      t1 = fmaf(W4[64 + j], h3, t1);
      t2 = fmaf(W4[128 + j], h3, t2);
    }
    out[3 * r + 0] = t0;
    out[3 * r + 1] = t1;
    out[3 * r + 2] = t2;
    float s0, c0v, s1, c1v, s12, c12;
    sincosf(t0, &s0, &c0v);
    sincosf(t1, &s1, &c1v);
    sincosf(t1 + t2, &s12, &c12);
    float A = fmaf(0.115f, c12, 0.12f * c1v);
    size_t o2 = (size_t)3 * B + 3 * r;
    out[o2 + 0] = c0v * A;
    out[o2 + 1] = s0 * A;
    out[o2 + 2] = fmaf(0.115f, s12, 0.12f * s1);
  }
}

// ===========================================================================

extern "C" void kernel_launch(void* const* d_in, const int* in_sizes, int n_in,
                              void* d_out, int out_size, void* d_ws, size_t ws_size,
                              hipStream_t stream) {
  const float* x = (const float*)d_in[0];
  const float* W1 = (const float*)d_in[1];
  const float* b1 = (const float*)d_in[2];
  const float* g1 = (const float*)d_in[3];
  const float* be1 = (const float*)d_in[4];
  const float* W2 = (const float*)d_in[5];
  const float* b2 = (const float*)d_in[6];
  const float* g2 = (const float*)d_in[7];
  const float* be2 = (const float*)d_in[8];
  const float* W3 = (const float*)d_in[9];
  const float* b3 = (const float*)d_in[10];
  const float* g3 = (const float*)d_in[11];
  const float* be3 = (const float*)d_in[12];
  const float* W4 = (const float*)d_in[13];
  const float* b4 = (const float*)d_in[14];
  float* ws = (float*)d_ws;
  float* out = (float*)d_out;
  int B = in_sizes[0] / 3;

  hipMemsetAsync(d_ws, 0, 272 * sizeof(float), stream);

  const int blocks = 1024, thr = 256;
  size_t need = 65536 + (size_t)B * 64 * 2;

  k_stats_x<<<blocks, thr, 0, stream>>>(x, ws, B);
  k_fin1<<<1, 64, 0, stream>>>(W1, b1, g1, be1, ws, B);

  if (ws_size >= need) {
    unsigned short* zb = (unsigned short*)ws + ZB_U16;
    k_z2<<<blocks, thr, 0, stream>>>(x, W2, b2, ws, zb, B);
    k_colstats<<<blocks, thr, 0, stream>>>(zb, ws + WS_SUM2, ws + WS_SSQ2, B);
    k_fin_bn<<<1, 64, 0, stream>>>(ws + WS_SUM2, ws + WS_SSQ2, g2, be2,
                                   ws + FP_S2, ws + FP_C2, B);
    k_z3<<<blocks, thr, 0, stream>>>(W3, b3, ws, zb, B);
    k_colstats<<<blocks, thr, 0, stream>>>(zb, ws + WS_SUM3, ws + WS_SSQ3, B);
    k_fin_bn<<<1, 64, 0, stream>>>(ws + WS_SUM3, ws + WS_SSQ3, g3, be3,
                                   ws + FP_S3, ws + FP_C3, B);
    k_final_fast<<<blocks, thr, 0, stream>>>(zb, W4, b4, ws, out, B);
  } else {
    k_stats2_rc<<<blocks, thr, 0, stream>>>(x, W2, b2, ws, B);
    k_fin_dense_rc<<<1, 64, 0, stream>>>(W2, b2, g2, be2, ws + WS_SUM2, ws + WS_SSQ2,
                                         ws + RC_W2P, ws + RC_C2, B);
    k_stats3_rc<<<blocks, thr, 0, stream>>>(x, W3, b3, ws, B);
    k_fin_dense_rc<<<1, 64, 0, stream>>>(W3, b3, g3, be3, ws + WS_SUM3, ws + WS_SSQ3,
                                         ws + RC_W3P, ws + RC_C3, B);
    k_final_rc<<<blocks, thr, 0, stream>>>(x, W4, b4, ws, out, B);
  }
}

// Round 6
// 846.333 us; speedup vs baseline: 2.2730x; 1.2335x over previous
//
#include <hip/hip_runtime.h>
#include <math.h>

// ---------------------------------------------------------------------------
// InvKin, fp32-VALU pipeline with bf16 z-materialization (R5).
// R4 passed (1044 us); k_z2/k_z3 are VALU-issue-bound (VALUBusy 65%, HBM 5%)
// with ~4x more VALU cycles than the FMA floor. R5 attacks that:
//   * row-pairing: each thread computes 2 consecutive rows -> every weight
//     load feeds 2 FMAs (halves per-row load/address ops)
//   * float2 packed math (v_pk_fma_f32) -> halves FMA instruction count
//   * __launch_bounds__(256,3) caps VGPRs (~170) so h[64] float2 fits
// Pipeline unchanged:
//   P1 k_stats_x : x second moments (layer-1 BN stats analytic)
//   P2 k_fin1    : fold BN1 -> fp32 W1p[64][3] + c1[64]
//   P3 k_z2      : h1 -> raw z2 -> bf16 zbuf[B][64]
//   P4 k_colstats: coalesced per-unit sum/ssq of zbuf
//   P5 k_fin_bn  : s2,c2
//   P6 k_z3      : h2 = relu(s2*z2+c2); z3 = W3 h2 + b3 in place
//   P7 k_colstats: stats of z3
//   P8 k_fin_bn  : s3,c3
//   P9 k_final   : h3 -> head -> closed-form FK -> out
// Fallback path (small ws): exact R1 kernel set (verified PASS).
// ---------------------------------------------------------------------------

static constexpr float kEps = 1e-5f;

typedef __attribute__((ext_vector_type(2))) float f32x2;

// shared ws fp32 indices (both paths)
#define WS_STAT9 0
#define WS_SUM2  16
#define WS_SSQ2  80
#define WS_SUM3  144
#define WS_SSQ3  208
#define WS_W1P   288    // [64][3] fp32 (BN1-folded)
#define WS_C1    480    // [64]
// fast path only
#define FP_S2    8192
#define FP_C2    8256
#define FP_S3    8320
#define FP_C3    8384
// fallback (R1) only — may overlap FP_* since only one path ever runs
#define RC_W2P   544
#define RC_C2    4640
#define RC_W3P   4704
#define RC_C3    8800
// z buffer: byte offset 65536 (ushort index 32768)
#define ZB_U16   32768

__device__ __forceinline__ unsigned short f2bf(float f) {
  unsigned u = __builtin_bit_cast(unsigned, f);
  u += 0x7fffu + ((u >> 16) & 1u);
  return (unsigned short)(u >> 16);
}
__device__ __forceinline__ unsigned packbf2(float a, float b) {
  return (unsigned)f2bf(a) | ((unsigned)f2bf(b) << 16);
}
__device__ __forceinline__ void unpack2(unsigned w, float& lo, float& hi) {
  lo = __builtin_bit_cast(float, w << 16);
  hi = __builtin_bit_cast(float, w & 0xffff0000u);
}
__device__ __forceinline__ float bfbits(unsigned short s) {
  unsigned u = ((unsigned)s) << 16;
  return __builtin_bit_cast(float, u);
}
__device__ __forceinline__ f32x2 splat2(float v) {
  f32x2 r; r.x = v; r.y = v; return r;
}
__device__ __forceinline__ f32x2 vmax0(f32x2 v) {
  f32x2 r; r.x = fmaxf(v.x, 0.f); r.y = fmaxf(v.y, 0.f); return r;
}

__device__ __forceinline__ float wred64(float v) {
  v += __shfl_xor(v, 32, 64);
  v += __shfl_xor(v, 16, 64);
  v += __shfl_xor(v, 8, 64);
  v += __shfl_xor(v, 4, 64);
  v += __shfl_xor(v, 2, 64);
  v += __shfl_xor(v, 1, 64);
  return v;
}

// packed dual-row dot: (zA,zB) = sum_k w[k] * (hA[k],hB[k])
__device__ __forceinline__ f32x2 dot64v(const float* __restrict__ wr,
                                        const f32x2* __restrict__ h) {
  f32x2 a0 = splat2(0.f), a1 = splat2(0.f), a2 = splat2(0.f), a3 = splat2(0.f);
#pragma unroll
  for (int k = 0; k < 64; k += 4) {
    a0 += splat2(wr[k + 0]) * h[k + 0];
    a1 += splat2(wr[k + 1]) * h[k + 1];
    a2 += splat2(wr[k + 2]) * h[k + 2];
    a3 += splat2(wr[k + 3]) * h[k + 3];
  }
  return (a0 + a1) + (a2 + a3);
}

__device__ __forceinline__ float dot64(const float* __restrict__ wr,
                                       const float hin[64]) {
  float a0 = 0.f, a1 = 0.f, a2 = 0.f, a3 = 0.f;
#pragma unroll
  for (int k = 0; k < 64; k += 4) {
    a0 = fmaf(wr[k + 0], hin[k + 0], a0);
    a1 = fmaf(wr[k + 1], hin[k + 1], a1);
    a2 = fmaf(wr[k + 2], hin[k + 2], a2);
    a3 = fmaf(wr[k + 3], hin[k + 3], a3);
  }
  return (a0 + a1) + (a2 + a3);
}

// ---- P1: x second moments (shared) ---------------------------------------
__global__ void __launch_bounds__(256) k_stats_x(const float* __restrict__ x,
                                                 float* __restrict__ ws, int B) {
  int tid = blockIdx.x * 256 + threadIdx.x;
  int nt = gridDim.x * 256;
  float s0 = 0.f, s1 = 0.f, s2 = 0.f;
  float q00 = 0.f, q01 = 0.f, q02 = 0.f, q11 = 0.f, q12 = 0.f, q22 = 0.f;
  for (int r = tid; r < B; r += nt) {
    float x0 = x[3 * r], x1 = x[3 * r + 1], x2 = x[3 * r + 2];
    s0 += x0; s1 += x1; s2 += x2;
    q00 = fmaf(x0, x0, q00); q01 = fmaf(x0, x1, q01); q02 = fmaf(x0, x2, q02);
    q11 = fmaf(x1, x1, q11); q12 = fmaf(x1, x2, q12); q22 = fmaf(x2, x2, q22);
  }
  s0 = wred64(s0); s1 = wred64(s1); s2 = wred64(s2);
  q00 = wred64(q00); q01 = wred64(q01); q02 = wred64(q02);
  q11 = wred64(q11); q12 = wred64(q12); q22 = wred64(q22);
  __shared__ float part[9];
  if (threadIdx.x < 9) part[threadIdx.x] = 0.f;
  __syncthreads();
  if ((threadIdx.x & 63) == 0) {
    atomicAdd(&part[0], s0); atomicAdd(&part[1], s1); atomicAdd(&part[2], s2);
    atomicAdd(&part[3], q00); atomicAdd(&part[4], q01); atomicAdd(&part[5], q02);
    atomicAdd(&part[6], q11); atomicAdd(&part[7], q12); atomicAdd(&part[8], q22);
  }
  __syncthreads();
  if (threadIdx.x < 9) atomicAdd(&ws[WS_STAT9 + threadIdx.x], part[threadIdx.x]);
}

// ---- P2: fold BN1 (shared) ------------------------------------------------
__global__ void k_fin1(const float* __restrict__ W1, const float* __restrict__ b1,
                       const float* __restrict__ g1, const float* __restrict__ be1,
                       float* __restrict__ ws, int B) {
  int j = threadIdx.x;  // 64
  float inv = 1.0f / (float)B;
  float ex0 = ws[0] * inv, ex1 = ws[1] * inv, ex2 = ws[2] * inv;
  float c00 = ws[3] * inv - ex0 * ex0;
  float c01 = ws[4] * inv - ex0 * ex1;
  float c02 = ws[5] * inv - ex0 * ex2;
  float c11 = ws[6] * inv - ex1 * ex1;
  float c12 = ws[7] * inv - ex1 * ex2;
  float c22 = ws[8] * inv - ex2 * ex2;
  float w0 = W1[3 * j], w1 = W1[3 * j + 1], w2 = W1[3 * j + 2];
  float mean = w0 * ex0 + w1 * ex1 + w2 * ex2 + b1[j];
  float var = w0 * w0 * c00 + w1 * w1 * c11 + w2 * w2 * c22 +
              2.f * (w0 * w1 * c01 + w0 * w2 * c02 + w1 * w2 * c12);
  float s = g1[j] * rsqrtf(var + kEps);
  ws[WS_W1P + 3 * j + 0] = s * w0;
  ws[WS_W1P + 3 * j + 1] = s * w1;
  ws[WS_W1P + 3 * j + 2] = s * w2;
  ws[WS_C1 + j] = fmaf(s, b1[j] - mean, be1[j]);
}

// =========================== FAST PATH =====================================

// ---- P3: z2 = W2 h1 + b2 -> bf16 zbuf (2 rows/thread, packed) ------------
__global__ void __launch_bounds__(256, 3) k_z2(const float* __restrict__ x,
                                               const float* __restrict__ W2,
                                               const float* __restrict__ b2,
                                               const float* __restrict__ ws,
                                               unsigned short* __restrict__ zb, int B) {
  const float* W1p = ws + WS_W1P;
  const float* c1 = ws + WS_C1;
  int tid = blockIdx.x * 256 + threadIdx.x;
  int nt = gridDim.x * 256;
  int npair = (B + 1) >> 1;
  for (int p = tid; p < npair; p += nt) {
    int r0 = 2 * p;
    int r1 = (r0 + 1 < B) ? (r0 + 1) : r0;
    f32x2 xv0, xv1, xv2;
    xv0.x = x[3 * r0];     xv0.y = x[3 * r1];
    xv1.x = x[3 * r0 + 1]; xv1.y = x[3 * r1 + 1];
    xv2.x = x[3 * r0 + 2]; xv2.y = x[3 * r1 + 2];
    f32x2 h[64];
#pragma unroll
    for (int k = 0; k < 64; ++k) {
      f32x2 z = splat2(c1[k]);
      z += splat2(W1p[3 * k + 0]) * xv0;
      z += splat2(W1p[3 * k + 1]) * xv1;
      z += splat2(W1p[3 * k + 2]) * xv2;
      h[k] = vmax0(z);
    }
    uint4* zrA = (uint4*)(zb + (size_t)r0 * 64);
    uint4* zrB = (uint4*)(zb + (size_t)r1 * 64);
#pragma unroll 1
    for (int jb = 0; jb < 8; ++jb) {
      f32x2 z[8];
#pragma unroll
      for (int u = 0; u < 8; ++u) {
        int j = jb * 8 + u;
        z[u] = dot64v(W2 + j * 64, h) + splat2(b2[j]);
      }
      uint4 oA, oB;
      oA.x = packbf2(z[0].x, z[1].x); oA.y = packbf2(z[2].x, z[3].x);
      oA.z = packbf2(z[4].x, z[5].x); oA.w = packbf2(z[6].x, z[7].x);
      oB.x = packbf2(z[0].y, z[1].y); oB.y = packbf2(z[2].y, z[3].y);
      oB.z = packbf2(z[4].y, z[5].y); oB.w = packbf2(z[6].y, z[7].y);
      zrA[jb] = oA;
      zrB[jb] = oB;
    }
  }
}

// ---- P4/P7: coalesced per-unit sum/ssq of zbuf ---------------------------
__global__ void __launch_bounds__(256) k_colstats(const unsigned short* __restrict__ zb,
                                                  float* __restrict__ sumg,
                                                  float* __restrict__ ssqg, int B) {
  int u = threadIdx.x & 63;
  int rloc = threadIdx.x >> 6;              // 0..3
  int rstep = gridDim.x * 4;
  float accS = 0.f, accQ = 0.f;
  for (int r = blockIdx.x * 4 + rloc; r < B; r += rstep) {
    float z = bfbits(zb[(size_t)r * 64 + u]);
    accS += z;
    accQ = fmaf(z, z, accQ);
  }
  __shared__ float sS[64], sQ[64];
  if (threadIdx.x < 64) { sS[threadIdx.x] = 0.f; sQ[threadIdx.x] = 0.f; }
  __syncthreads();
  atomicAdd(&sS[u], accS);
  atomicAdd(&sQ[u], accQ);
  __syncthreads();
  if (threadIdx.x < 64) {
    atomicAdd(&sumg[threadIdx.x], sS[threadIdx.x]);
    atomicAdd(&ssqg[threadIdx.x], sQ[threadIdx.x]);
  }
}

// ---- P5/P8: BN scale/shift only ------------------------------------------
__global__ void k_fin_bn(const float* __restrict__ sum, const float* __restrict__ ssq,
                         const float* __restrict__ g, const float* __restrict__ be,
                         float* __restrict__ sOut, float* __restrict__ cOut, int B) {
  int j = threadIdx.x;  // 64
  float inv = 1.0f / (float)B;
  float mean = sum[j] * inv;
  float var = ssq[j] * inv - mean * mean;
  float s = g[j] * rsqrtf(var + kEps);
  sOut[j] = s;
  cOut[j] = fmaf(-s, mean, be[j]);
}

// ---- P6: z3 = W3 relu(s2*z2+c2) + b3, in place (2 rows/thread) -----------
__global__ void __launch_bounds__(256, 3) k_z3(const float* __restrict__ W3,
                                               const float* __restrict__ b3,
                                               const float* __restrict__ ws,
                                               unsigned short* __restrict__ zb, int B) {
  const float* s2 = ws + FP_S2;
  const float* c2 = ws + FP_C2;
  int tid = blockIdx.x * 256 + threadIdx.x;
  int nt = gridDim.x * 256;
  int npair = (B + 1) >> 1;
  for (int p = tid; p < npair; p += nt) {
    int r0 = 2 * p;
    int r1 = (r0 + 1 < B) ? (r0 + 1) : r0;
    uint4* zrA = (uint4*)(zb + (size_t)r0 * 64);
    uint4* zrB = (uint4*)(zb + (size_t)r1 * 64);
    f32x2 h[64];
#pragma unroll
    for (int jb = 0; jb < 8; ++jb) {
      uint4 vA = zrA[jb], vB = zrB[jb];
      float a0, a1, b0v, b1v;
      unpack2(vA.x, a0, a1); unpack2(vB.x, b0v, b1v);
      h[jb * 8 + 0].x = a0; h[jb * 8 + 0].y = b0v;
      h[jb * 8 + 1].x = a1; h[jb * 8 + 1].y = b1v;
      unpack2(vA.y, a0, a1); unpack2(vB.y, b0v, b1v);
      h[jb * 8 + 2].x = a0; h[jb * 8 + 2].y = b0v;
      h[jb * 8 + 3].x = a1; h[jb * 8 + 3].y = b1v;
      unpack2(vA.z, a0, a1); unpack2(vB.z, b0v, b1v);
      h[jb * 8 + 4].x = a0; h[jb * 8 + 4].y = b0v;
      h[jb * 8 + 5].x = a1; h[jb * 8 + 5].y = b1v;
      unpack2(vA.w, a0, a1); unpack2(vB.w, b0v, b1v);
      h[jb * 8 + 6].x = a0; h[jb * 8 + 6].y = b0v;
      h[jb * 8 + 7].x = a1; h[jb * 8 + 7].y = b1v;
    }
#pragma unroll
    for (int k = 0; k < 64; ++k)
      h[k] = vmax0(splat2(s2[k]) * h[k] + splat2(c2[k]));
#pragma unroll 1
    for (int jb = 0; jb < 8; ++jb) {
      f32x2 z[8];
#pragma unroll
      for (int u = 0; u < 8; ++u) {
        int j = jb * 8 + u;
        z[u] = dot64v(W3 + j * 64, h) + splat2(b3[j]);
      }
      uint4 oA, oB;
      oA.x = packbf2(z[0].x, z[1].x); oA.y = packbf2(z[2].x, z[3].x);
      oA.z = packbf2(z[4].x, z[5].x); oA.w = packbf2(z[6].x, z[7].x);
      oB.x = packbf2(z[0].y, z[1].y); oB.y = packbf2(z[2].y, z[3].y);
      oB.z = packbf2(z[4].y, z[5].y); oB.w = packbf2(z[6].y, z[7].y);
      zrA[jb] = oA;
      zrB[jb] = oB;
    }
  }
}

// ---- P9: h3 -> head -> FK -> out (2 rows/thread) --------------------------
__global__ void __launch_bounds__(256, 3) k_final_fast(const unsigned short* __restrict__ zb,
                                                       const float* __restrict__ W4,
                                                       const float* __restrict__ b4,
                                                       const float* __restrict__ ws,
                                                       float* __restrict__ out, int B) {
  const float* s3 = ws + FP_S3;
  const float* c3 = ws + FP_C3;
  int tid = blockIdx.x * 256 + threadIdx.x;
  int nt = gridDim.x * 256;
  int npair = (B + 1) >> 1;
  for (int p = tid; p < npair; p += nt) {
    int r0 = 2 * p;
    int r1 = (r0 + 1 < B) ? (r0 + 1) : r0;
    const uint4* zrA = (const uint4*)(zb + (size_t)r0 * 64);
    const uint4* zrB = (const uint4*)(zb + (size_t)r1 * 64);
    f32x2 h[64];
#pragma unroll
    for (int jb = 0; jb < 8; ++jb) {
      uint4 vA = zrA[jb], vB = zrB[jb];
      float a0, a1, b0v, b1v;
      unpack2(vA.x, a0, a1); unpack2(vB.x, b0v, b1v);
      h[jb * 8 + 0].x = a0; h[jb * 8 + 0].y = b0v;
      h[jb * 8 + 1].x = a1; h[jb * 8 + 1].y = b1v;
      unpack2(vA.y, a0, a1); unpack2(vB.y, b0v, b1v);
      h[jb * 8 + 2].x = a0; h[jb * 8 + 2].y = b0v;
      h[jb * 8 + 3].x = a1; h[jb * 8 + 3].y = b1v;
      unpack2(vA.z, a0, a1); unpack2(vB.z, b0v, b1v);
      h[jb * 8 + 4].x = a0; h[jb * 8 + 4].y = b0v;
      h[jb * 8 + 5].x = a1; h[jb * 8 + 5].y = b1v;
      unpack2(vA.w, a0, a1); unpack2(vB.w, b0v, b1v);
      h[jb * 8 + 6].x = a0; h[jb * 8 + 6].y = b0v;
      h[jb * 8 + 7].x = a1; h[jb * 8 + 7].y = b1v;
    }
#pragma unroll
    for (int k = 0; k < 64; ++k)
      h[k] = vmax0(splat2(s3[k]) * h[k] + splat2(c3[k]));
    f32x2 t0 = dot64v(W4, h) + splat2(b4[0]);
    f32x2 t1 = dot64v(W4 + 64, h) + splat2(b4[1]);
    f32x2 t2 = dot64v(W4 + 128, h) + splat2(b4[2]);
    // row A
    {
      out[3 * r0 + 0] = t0.x;
      out[3 * r0 + 1] = t1.x;
      out[3 * r0 + 2] = t2.x;
      float s0, c0v, s1, c1v, s12, c12;
      sincosf(t0.x, &s0, &c0v);
      sincosf(t1.x, &s1, &c1v);
      sincosf(t1.x + t2.x, &s12, &c12);
      float A = fmaf(0.115f, c12, 0.12f * c1v);
      size_t o2 = (size_t)3 * B + 3 * r0;
      out[o2 + 0] = c0v * A;
      out[o2 + 1] = s0 * A;
      out[o2 + 2] = fmaf(0.115f, s12, 0.12f * s1);
    }
    if (r1 != r0) {
      out[3 * r1 + 0] = t0.y;
      out[3 * r1 + 1] = t1.y;
      out[3 * r1 + 2] = t2.y;
      float s0, c0v, s1, c1v, s12, c12;
      sincosf(t0.y, &s0, &c0v);
      sincosf(t1.y, &s1, &c1v);
      sincosf(t1.y + t2.y, &s12, &c12);
      float A = fmaf(0.115f, c12, 0.12f * c1v);
      size_t o2 = (size_t)3 * B + 3 * r1;
      out[o2 + 0] = c0v * A;
      out[o2 + 1] = s0 * A;
      out[o2 + 2] = fmaf(0.115f, s12, 0.12f * s1);
    }
  }
}

// ========================= FALLBACK (R1, verified) =========================

__device__ __forceinline__ void layer1_eval(const float* __restrict__ W1p,
                                            const float* __restrict__ c1,
                                            float x0, float x1, float x2,
                                            float h[64]) {
#pragma unroll
  for (int j = 0; j < 64; ++j) {
    float z = fmaf(W1p[3 * j + 2], x2,
               fmaf(W1p[3 * j + 1], x1, fmaf(W1p[3 * j], x0, c1[j])));
    h[j] = fmaxf(z, 0.f);
  }
}

__device__ __forceinline__ void dense_relu_rc(const float* __restrict__ Wp,
                                              const float* __restrict__ c,
                                              const float hin[64], float hout[64]) {
#pragma unroll
  for (int j = 0; j < 64; ++j)
    hout[j] = fmaxf(dot64(Wp + j * 64, hin) + c[j], 0.f);
}

__device__ __forceinline__ void dense_stats_rc(const float* __restrict__ W,
                                               const float* __restrict__ b,
                                               const float hin[64], int lane,
                                               float valid, float& accS, float& accQ) {
#pragma unroll 1
  for (int j = 0; j < 64; ++j) {
    float z = (dot64(W + j * 64, hin) + b[j]) * valid;
    float rs = wred64(z);
    float rq = wred64(z * z);
    accS += (lane == j) ? rs : 0.f;
    accQ += (lane == j) ? rq : 0.f;
  }
}

__device__ __forceinline__ void block_combine_rc(float accS, float accQ,
                                                 float* __restrict__ sumg,
                                                 float* __restrict__ ssqg) {
  __shared__ float sS[256], sQ[256];
  sS[threadIdx.x] = accS;
  sQ[threadIdx.x] = accQ;
  __syncthreads();
  if (threadIdx.x < 64) {
    float S = sS[threadIdx.x] + sS[threadIdx.x + 64] + sS[threadIdx.x + 128] + sS[threadIdx.x + 192];
    float Q = sQ[threadIdx.x] + sQ[threadIdx.x + 64] + sQ[threadIdx.x + 128] + sQ[threadIdx.x + 192];
    atomicAdd(&sumg[threadIdx.x], S);
    atomicAdd(&ssqg[threadIdx.x], Q);
  }
}

__global__ void __launch_bounds__(256) k_stats2_rc(const float* __restrict__ x,
                                                   const float* __restrict__ W2,
                                                   const float* __restrict__ b2,
                                                   float* __restrict__ ws, int B) {
  const float* W1p = ws + WS_W1P;
  const float* c1 = ws + WS_C1;
  int tid = blockIdx.x * 256 + threadIdx.x;
  int nt = gridDim.x * 256;
  int lane = threadIdx.x & 63;
  float accS = 0.f, accQ = 0.f;
  int iters = (B + nt - 1) / nt;
  for (int it = 0; it < iters; ++it) {
    int r = tid + it * nt;
    float valid = (r < B) ? 1.f : 0.f;
    int rc = (r < B) ? r : (B - 1);
    float h1[64];
    layer1_eval(W1p, c1, x[3 * rc], x[3 * rc + 1], x[3 * rc + 2], h1);
    dense_stats_rc(W2, b2, h1, lane, valid, accS, accQ);
  }
  block_combine_rc(accS, accQ, ws + WS_SUM2, ws + WS_SSQ2);
}

__global__ void k_fin_dense_rc(const float* __restrict__ W, const float* __restrict__ b,
                               const float* __restrict__ g, const float* __restrict__ be,
                               const float* __restrict__ sum, const float* __restrict__ ssq,
                               float* __restrict__ Wp, float* __restrict__ cc, int B) {
  int j = threadIdx.x;
  float inv = 1.0f / (float)B;
  float mean = sum[j] * inv;
  float var = ssq[j] * inv - mean * mean;
  float s = g[j] * rsqrtf(var + kEps);
  for (int k = 0; k < 64; ++k) Wp[j * 64 + k] = s * W[j * 64 + k];
  cc[j] = fmaf(s, b[j] - mean, be[j]);
}

__global__ void __launch_bounds__(256) k_stats3_rc(const float* __restrict__ x,
                                                   const float* __restrict__ W3,
                                                   const float* __restrict__ b3,
                                                   float* __restrict__ ws, int B) {
  const float* W1p = ws + WS_W1P;
  const float* c1 = ws + WS_C1;
  const float* W2p = ws + RC_W2P;
  const float* c2 = ws + RC_C2;
  int tid = blockIdx.x * 256 + threadIdx.x;
  int nt = gridDim.x * 256;
  int lane = threadIdx.x & 63;
  float accS = 0.f, accQ = 0.f;
  int iters = (B + nt - 1) / nt;
  for (int it = 0; it < iters; ++it) {
    int r = tid + it * nt;
    float valid = (r < B) ? 1.f : 0.f;
    int rc = (r < B) ? r : (B - 1);
    float h1[64], h2[64];
    layer1_eval(W1p, c1, x[3 * rc], x[3 * rc + 1], x[3 * rc + 2], h1);
    dense_relu_rc(W2p, c2, h1, h2);
    dense_stats_rc(W3, b3, h2, lane, valid, accS, accQ);
  }
  block_combine_rc(accS, accQ, ws + WS_SUM3, ws + WS_SSQ3);
}

__global__ void __launch_bounds__(256) k_final_rc(const float* __restrict__ x,
                                                  const float* __restrict__ W4,
                                                  const float* __restrict__ b4,
                                                  const float* __restrict__ ws,
                                                  float* __restrict__ out, int B) {
  const float* W1p = ws + WS_W1P;
  const float* c1 = ws + WS_C1;
  const float* W2p = ws + RC_W2P;
  const float* c2 = ws + RC_C2;
  const float* W3p = ws + RC_W3P;
  const float* c3 = ws + RC_C3;
  int tid = blockIdx.x * 256 + threadIdx.x;
  int nt = gridDim.x * 256;
  for (int r = tid; r < B; r += nt) {
    float h1[64], h2[64];
    layer1_eval(W1p, c1, x[3 * r], x[3 * r + 1], x[3 * r + 2], h1);
    dense_relu_rc(W2p, c2, h1, h2);
    float t0 = b4[0], t1 = b4[1], t2 = b4[2];
#pragma unroll 1
    for (int j = 0; j < 64; ++j) {
      float h3 = fmaxf(dot64(W3p + j * 64, h2) + c3[j], 0.f);
      t0 = fmaf(W4[j], h3, t0);
      t1 = fmaf(W4[64 + j], h3, t1);
      t2 = fmaf(W4[128 + j], h3, t2);
    }
    out[3 * r + 0] = t0;
    out[3 * r + 1] = t1;
    out[3 * r + 2] = t2;
    float s0, c0v, s1, c1v, s12, c12;
    sincosf(t0, &s0, &c0v);
    sincosf(t1, &s1, &c1v);
    sincosf(t1 + t2, &s12, &c12);
    float A = fmaf(0.115f, c12, 0.12f * c1v);
    size_t o2 = (size_t)3 * B + 3 * r;
    out[o2 + 0] = c0v * A;
    out[o2 + 1] = s0 * A;
    out[o2 + 2] = fmaf(0.115f, s12, 0.12f * s1);
  }
}

// ===========================================================================

extern "C" void kernel_launch(void* const* d_in, const int* in_sizes, int n_in,
                              void* d_out, int out_size, void* d_ws, size_t ws_size,
                              hipStream_t stream) {
  const float* x = (const float*)d_in[0];
  const float* W1 = (const float*)d_in[1];
  const float* b1 = (const float*)d_in[2];
  const float* g1 = (const float*)d_in[3];
  const float* be1 = (const float*)d_in[4];
  const float* W2 = (const float*)d_in[5];
  const float* b2 = (const float*)d_in[6];
  const float* g2 = (const float*)d_in[7];
  const float* be2 = (const float*)d_in[8];
  const float* W3 = (const float*)d_in[9];
  const float* b3 = (const float*)d_in[10];
  const float* g3 = (const float*)d_in[11];
  const float* be3 = (const float*)d_in[12];
  const float* W4 = (const float*)d_in[13];
  const float* b4 = (const float*)d_in[14];
  float* ws = (float*)d_ws;
  float* out = (float*)d_out;
  int B = in_sizes[0] / 3;

  hipMemsetAsync(d_ws, 0, 272 * sizeof(float), stream);

  const int blocks = 1024, thr = 256;
  const int zblocks = 2048;
  size_t need = 65536 + (size_t)B * 64 * 2;

  k_stats_x<<<blocks, thr, 0, stream>>>(x, ws, B);
  k_fin1<<<1, 64, 0, stream>>>(W1, b1, g1, be1, ws, B);

  if (ws_size >= need) {
    unsigned short* zb = (unsigned short*)ws + ZB_U16;
    k_z2<<<zblocks, thr, 0, stream>>>(x, W2, b2, ws, zb, B);
    k_colstats<<<blocks, thr, 0, stream>>>(zb, ws + WS_SUM2, ws + WS_SSQ2, B);
    k_fin_bn<<<1, 64, 0, stream>>>(ws + WS_SUM2, ws + WS_SSQ2, g2, be2,
                                   ws + FP_S2, ws + FP_C2, B);
    k_z3<<<zblocks, thr, 0, stream>>>(W3, b3, ws, zb, B);
    k_colstats<<<blocks, thr, 0, stream>>>(zb, ws + WS_SUM3, ws + WS_SSQ3, B);
    k_fin_bn<<<1, 64, 0, stream>>>(ws + WS_SUM3, ws + WS_SSQ3, g3, be3,
                                   ws + FP_S3, ws + FP_C3, B);
    k_final_fast<<<zblocks, thr, 0, stream>>>(zb, W4, b4, ws, out, B);
  } else {
    k_stats2_rc<<<blocks, thr, 0, stream>>>(x, W2, b2, ws, B);
    k_fin_dense_rc<<<1, 64, 0, stream>>>(W2, b2, g2, be2, ws + WS_SUM2, ws + WS_SSQ2,
                                         ws + RC_W2P, ws + RC_C2, B);
    k_stats3_rc<<<blocks, thr, 0, stream>>>(x, W3, b3, ws, B);
    k_fin_dense_rc<<<1, 64, 0, stream>>>(W3, b3, g3, be3, ws + WS_SUM3, ws + WS_SSQ3,
                                         ws + RC_W3P, ws + RC_C3, B);
    k_final_rc<<<blocks, thr, 0, stream>>>(x, W4, b4, ws, out, B);
  }
}

// Round 7
// 742.572 us; speedup vs baseline: 2.5906x; 1.1397x over previous
//
#include <hip/hip_runtime.h>
#include <math.h>

// ---------------------------------------------------------------------------
// InvKin, fp32-VALU pipeline with bf16 z-materialization (R6).
// R5 result: k_z3 VGPR=84 => compiler spilled f32x2 h[64] (128 regs) to
// scratch -> 390 MB phantom HBM write traffic, VALUBusy 26%. R6 changes ONE
// variable: __launch_bounds__(256,2) (~256-reg cap) on k_z2/k_z3/k_final so
// h lives in registers. Everything else identical to R5.
//   P1 k_stats_x : x second moments (layer-1 BN stats analytic)
//   P2 k_fin1    : fold BN1 -> fp32 W1p[64][3] + c1[64]
//   P3 k_z2      : h1 -> raw z2 -> bf16 zbuf[B][64]   (2 rows/thread, pk math)
//   P4 k_colstats: coalesced per-unit sum/ssq of zbuf
//   P5 k_fin_bn  : s2,c2
//   P6 k_z3      : h2 = relu(s2*z2+c2); z3 = W3 h2 + b3 in place
//   P7 k_colstats: stats of z3
//   P8 k_fin_bn  : s3,c3
//   P9 k_final   : h3 -> head -> closed-form FK -> out
// Fallback path (small ws): exact R1 kernel set (verified PASS).
// ---------------------------------------------------------------------------

static constexpr float kEps = 1e-5f;

typedef __attribute__((ext_vector_type(2))) float f32x2;

// shared ws fp32 indices (both paths)
#define WS_STAT9 0
#define WS_SUM2  16
#define WS_SSQ2  80
#define WS_SUM3  144
#define WS_SSQ3  208
#define WS_W1P   288    // [64][3] fp32 (BN1-folded)
#define WS_C1    480    // [64]
// fast path only
#define FP_S2    8192
#define FP_C2    8256
#define FP_S3    8320
#define FP_C3    8384
// fallback (R1) only — may overlap FP_* since only one path ever runs
#define RC_W2P   544
#define RC_C2    4640
#define RC_W3P   4704
#define RC_C3    8800
// z buffer: byte offset 65536 (ushort index 32768)
#define ZB_U16   32768

__device__ __forceinline__ unsigned short f2bf(float f) {
  unsigned u = __builtin_bit_cast(unsigned, f);
  u += 0x7fffu + ((u >> 16) & 1u);
  return (unsigned short)(u >> 16);
}
__device__ __forceinline__ unsigned packbf2(float a, float b) {
  return (unsigned)f2bf(a) | ((unsigned)f2bf(b) << 16);
}
__device__ __forceinline__ void unpack2(unsigned w, float& lo, float& hi) {
  lo = __builtin_bit_cast(float, w << 16);
  hi = __builtin_bit_cast(float, w & 0xffff0000u);
}
__device__ __forceinline__ float bfbits(unsigned short s) {
  unsigned u = ((unsigned)s) << 16;
  return __builtin_bit_cast(float, u);
}
__device__ __forceinline__ f32x2 splat2(float v) {
  f32x2 r; r.x = v; r.y = v; return r;
}
__device__ __forceinline__ f32x2 vmax0(f32x2 v) {
  f32x2 r; r.x = fmaxf(v.x, 0.f); r.y = fmaxf(v.y, 0.f); return r;
}

__device__ __forceinline__ float wred64(float v) {
  v += __shfl_xor(v, 32, 64);
  v += __shfl_xor(v, 16, 64);
  v += __shfl_xor(v, 8, 64);
  v += __shfl_xor(v, 4, 64);
  v += __shfl_xor(v, 2, 64);
  v += __shfl_xor(v, 1, 64);
  return v;
}

// packed dual-row dot: (zA,zB) = sum_k w[k] * (hA[k],hB[k])
__device__ __forceinline__ f32x2 dot64v(const float* __restrict__ wr,
                                        const f32x2* __restrict__ h) {
  f32x2 a0 = splat2(0.f), a1 = splat2(0.f), a2 = splat2(0.f), a3 = splat2(0.f);
#pragma unroll
  for (int k = 0; k < 64; k += 4) {
    a0 += splat2(wr[k + 0]) * h[k + 0];
    a1 += splat2(wr[k + 1]) * h[k + 1];
    a2 += splat2(wr[k + 2]) * h[k + 2];
    a3 += splat2(wr[k + 3]) * h[k + 3];
  }
  return (a0 + a1) + (a2 + a3);
}

__device__ __forceinline__ float dot64(const float* __restrict__ wr,
                                       const float hin[64]) {
  float a0 = 0.f, a1 = 0.f, a2 = 0.f, a3 = 0.f;
#pragma unroll
  for (int k = 0; k < 64; k += 4) {
    a0 = fmaf(wr[k + 0], hin[k + 0], a0);
    a1 = fmaf(wr[k + 1], hin[k + 1], a1);
    a2 = fmaf(wr[k + 2], hin[k + 2], a2);
    a3 = fmaf(wr[k + 3], hin[k + 3], a3);
  }
  return (a0 + a1) + (a2 + a3);
}

// ---- P1: x second moments (shared) ---------------------------------------
__global__ void __launch_bounds__(256) k_stats_x(const float* __restrict__ x,
                                                 float* __restrict__ ws, int B) {
  int tid = blockIdx.x * 256 + threadIdx.x;
  int nt = gridDim.x * 256;
  float s0 = 0.f, s1 = 0.f, s2 = 0.f;
  float q00 = 0.f, q01 = 0.f, q02 = 0.f, q11 = 0.f, q12 = 0.f, q22 = 0.f;
  for (int r = tid; r < B; r += nt) {
    float x0 = x[3 * r], x1 = x[3 * r + 1], x2 = x[3 * r + 2];
    s0 += x0; s1 += x1; s2 += x2;
    q00 = fmaf(x0, x0, q00); q01 = fmaf(x0, x1, q01); q02 = fmaf(x0, x2, q02);
    q11 = fmaf(x1, x1, q11); q12 = fmaf(x1, x2, q12); q22 = fmaf(x2, x2, q22);
  }
  s0 = wred64(s0); s1 = wred64(s1); s2 = wred64(s2);
  q00 = wred64(q00); q01 = wred64(q01); q02 = wred64(q02);
  q11 = wred64(q11); q12 = wred64(q12); q22 = wred64(q22);
  __shared__ float part[9];
  if (threadIdx.x < 9) part[threadIdx.x] = 0.f;
  __syncthreads();
  if ((threadIdx.x & 63) == 0) {
    atomicAdd(&part[0], s0); atomicAdd(&part[1], s1); atomicAdd(&part[2], s2);
    atomicAdd(&part[3], q00); atomicAdd(&part[4], q01); atomicAdd(&part[5], q02);
    atomicAdd(&part[6], q11); atomicAdd(&part[7], q12); atomicAdd(&part[8], q22);
  }
  __syncthreads();
  if (threadIdx.x < 9) atomicAdd(&ws[WS_STAT9 + threadIdx.x], part[threadIdx.x]);
}

// ---- P2: fold BN1 (shared) ------------------------------------------------
__global__ void k_fin1(const float* __restrict__ W1, const float* __restrict__ b1,
                       const float* __restrict__ g1, const float* __restrict__ be1,
                       float* __restrict__ ws, int B) {
  int j = threadIdx.x;  // 64
  float inv = 1.0f / (float)B;
  float ex0 = ws[0] * inv, ex1 = ws[1] * inv, ex2 = ws[2] * inv;
  float c00 = ws[3] * inv - ex0 * ex0;
  float c01 = ws[4] * inv - ex0 * ex1;
  float c02 = ws[5] * inv - ex0 * ex2;
  float c11 = ws[6] * inv - ex1 * ex1;
  float c12 = ws[7] * inv - ex1 * ex2;
  float c22 = ws[8] * inv - ex2 * ex2;
  float w0 = W1[3 * j], w1 = W1[3 * j + 1], w2 = W1[3 * j + 2];
  float mean = w0 * ex0 + w1 * ex1 + w2 * ex2 + b1[j];
  float var = w0 * w0 * c00 + w1 * w1 * c11 + w2 * w2 * c22 +
              2.f * (w0 * w1 * c01 + w0 * w2 * c02 + w1 * w2 * c12);
  float s = g1[j] * rsqrtf(var + kEps);
  ws[WS_W1P + 3 * j + 0] = s * w0;
  ws[WS_W1P + 3 * j + 1] = s * w1;
  ws[WS_W1P + 3 * j + 2] = s * w2;
  ws[WS_C1 + j] = fmaf(s, b1[j] - mean, be1[j]);
}

// =========================== FAST PATH =====================================

// ---- P3: z2 = W2 h1 + b2 -> bf16 zbuf (2 rows/thread, packed) ------------
__global__ void __launch_bounds__(256, 2) k_z2(const float* __restrict__ x,
                                               const float* __restrict__ W2,
                                               const float* __restrict__ b2,
                                               const float* __restrict__ ws,
                                               unsigned short* __restrict__ zb, int B) {
  const float* W1p = ws + WS_W1P;
  const float* c1 = ws + WS_C1;
  int tid = blockIdx.x * 256 + threadIdx.x;
  int nt = gridDim.x * 256;
  int npair = (B + 1) >> 1;
  for (int p = tid; p < npair; p += nt) {
    int r0 = 2 * p;
    int r1 = (r0 + 1 < B) ? (r0 + 1) : r0;
    f32x2 xv0, xv1, xv2;
    xv0.x = x[3 * r0];     xv0.y = x[3 * r1];
    xv1.x = x[3 * r0 + 1]; xv1.y = x[3 * r1 + 1];
    xv2.x = x[3 * r0 + 2]; xv2.y = x[3 * r1 + 2];
    f32x2 h[64];
#pragma unroll
    for (int k = 0; k < 64; ++k) {
      f32x2 z = splat2(c1[k]);
      z += splat2(W1p[3 * k + 0]) * xv0;
      z += splat2(W1p[3 * k + 1]) * xv1;
      z += splat2(W1p[3 * k + 2]) * xv2;
      h[k] = vmax0(z);
    }
    uint4* zrA = (uint4*)(zb + (size_t)r0 * 64);
    uint4* zrB = (uint4*)(zb + (size_t)r1 * 64);
#pragma unroll 1
    for (int jb = 0; jb < 8; ++jb) {
      f32x2 z[8];
#pragma unroll
      for (int u = 0; u < 8; ++u) {
        int j = jb * 8 + u;
        z[u] = dot64v(W2 + j * 64, h) + splat2(b2[j]);
      }
      uint4 oA, oB;
      oA.x = packbf2(z[0].x, z[1].x); oA.y = packbf2(z[2].x, z[3].x);
      oA.z = packbf2(z[4].x, z[5].x); oA.w = packbf2(z[6].x, z[7].x);
      oB.x = packbf2(z[0].y, z[1].y); oB.y = packbf2(z[2].y, z[3].y);
      oB.z = packbf2(z[4].y, z[5].y); oB.w = packbf2(z[6].y, z[7].y);
      zrA[jb] = oA;
      zrB[jb] = oB;
    }
  }
}

// ---- P4/P7: coalesced per-unit sum/ssq of zbuf ---------------------------
__global__ void __launch_bounds__(256) k_colstats(const unsigned short* __restrict__ zb,
                                                  float* __restrict__ sumg,
                                                  float* __restrict__ ssqg, int B) {
  int u = threadIdx.x & 63;
  int rloc = threadIdx.x >> 6;              // 0..3
  int rstep = gridDim.x * 4;
  float accS = 0.f, accQ = 0.f;
  for (int r = blockIdx.x * 4 + rloc; r < B; r += rstep) {
    float z = bfbits(zb[(size_t)r * 64 + u]);
    accS += z;
    accQ = fmaf(z, z, accQ);
  }
  __shared__ float sS[64], sQ[64];
  if (threadIdx.x < 64) { sS[threadIdx.x] = 0.f; sQ[threadIdx.x] = 0.f; }
  __syncthreads();
  atomicAdd(&sS[u], accS);
  atomicAdd(&sQ[u], accQ);
  __syncthreads();
  if (threadIdx.x < 64) {
    atomicAdd(&sumg[threadIdx.x], sS[threadIdx.x]);
    atomicAdd(&ssqg[threadIdx.x], sQ[threadIdx.x]);
  }
}

// ---- P5/P8: BN scale/shift only ------------------------------------------
__global__ void k_fin_bn(const float* __restrict__ sum, const float* __restrict__ ssq,
                         const float* __restrict__ g, const float* __restrict__ be,
                         float* __restrict__ sOut, float* __restrict__ cOut, int B) {
  int j = threadIdx.x;  // 64
  float inv = 1.0f / (float)B;
  float mean = sum[j] * inv;
  float var = ssq[j] * inv - mean * mean;
  float s = g[j] * rsqrtf(var + kEps);
  sOut[j] = s;
  cOut[j] = fmaf(-s, mean, be[j]);
}

// ---- P6: z3 = W3 relu(s2*z2+c2) + b3, in place (2 rows/thread) -----------
__global__ void __launch_bounds__(256, 2) k_z3(const float* __restrict__ W3,
                                               const float* __restrict__ b3,
                                               const float* __restrict__ ws,
                                               unsigned short* __restrict__ zb, int B) {
  const float* s2 = ws + FP_S2;
  const float* c2 = ws + FP_C2;
  int tid = blockIdx.x * 256 + threadIdx.x;
  int nt = gridDim.x * 256;
  int npair = (B + 1) >> 1;
  for (int p = tid; p < npair; p += nt) {
    int r0 = 2 * p;
    int r1 = (r0 + 1 < B) ? (r0 + 1) : r0;
    uint4* zrA = (uint4*)(zb + (size_t)r0 * 64);
    uint4* zrB = (uint4*)(zb + (size_t)r1 * 64);
    f32x2 h[64];
#pragma unroll
    for (int jb = 0; jb < 8; ++jb) {
      uint4 vA = zrA[jb], vB = zrB[jb];
      float a0, a1, b0v, b1v;
      unpack2(vA.x, a0, a1); unpack2(vB.x, b0v, b1v);
      h[jb * 8 + 0].x = a0; h[jb * 8 + 0].y = b0v;
      h[jb * 8 + 1].x = a1; h[jb * 8 + 1].y = b1v;
      unpack2(vA.y, a0, a1); unpack2(vB.y, b0v, b1v);
      h[jb * 8 + 2].x = a0; h[jb * 8 + 2].y = b0v;
      h[jb * 8 + 3].x = a1; h[jb * 8 + 3].y = b1v;
      unpack2(vA.z, a0, a1); unpack2(vB.z, b0v, b1v);
      h[jb * 8 + 4].x = a0; h[jb * 8 + 4].y = b0v;
      h[jb * 8 + 5].x = a1; h[jb * 8 + 5].y = b1v;
      unpack2(vA.w, a0, a1); unpack2(vB.w, b0v, b1v);
      h[jb * 8 + 6].x = a0; h[jb * 8 + 6].y = b0v;
      h[jb * 8 + 7].x = a1; h[jb * 8 + 7].y = b1v;
    }
#pragma unroll
    for (int k = 0; k < 64; ++k)
      h[k] = vmax0(splat2(s2[k]) * h[k] + splat2(c2[k]));
#pragma unroll 1
    for (int jb = 0; jb < 8; ++jb) {
      f32x2 z[8];
#pragma unroll
      for (int u = 0; u < 8; ++u) {
        int j = jb * 8 + u;
        z[u] = dot64v(W3 + j * 64, h) + splat2(b3[j]);
      }
      uint4 oA, oB;
      oA.x = packbf2(z[0].x, z[1].x); oA.y = packbf2(z[2].x, z[3].x);
      oA.z = packbf2(z[4].x, z[5].x); oA.w = packbf2(z[6].x, z[7].x);
      oB.x = packbf2(z[0].y, z[1].y); oB.y = packbf2(z[2].y, z[3].y);
      oB.z = packbf2(z[4].y, z[5].y); oB.w = packbf2(z[6].y, z[7].y);
      zrA[jb] = oA;
      zrB[jb] = oB;
    }
  }
}

// ---- P9: h3 -> head -> FK -> out (2 rows/thread) --------------------------
__global__ void __launch_bounds__(256, 2) k_final_fast(const unsigned short* __restrict__ zb,
                                                       const float* __restrict__ W4,
                                                       const float* __restrict__ b4,
                                                       const float* __restrict__ ws,
                                                       float* __restrict__ out, int B) {
  const float* s3 = ws + FP_S3;
  const float* c3 = ws + FP_C3;
  int tid = blockIdx.x * 256 + threadIdx.x;
  int nt = gridDim.x * 256;
  int npair = (B + 1) >> 1;
  for (int p = tid; p < npair; p += nt) {
    int r0 = 2 * p;
    int r1 = (r0 + 1 < B) ? (r0 + 1) : r0;
    const uint4* zrA = (const uint4*)(zb + (size_t)r0 * 64);
    const uint4* zrB = (const uint4*)(zb + (size_t)r1 * 64);
    f32x2 h[64];
#pragma unroll
    for (int jb = 0; jb < 8; ++jb) {
      uint4 vA = zrA[jb], vB = zrB[jb];
      float a0, a1, b0v, b1v;
      unpack2(vA.x, a0, a1); unpack2(vB.x, b0v, b1v);
      h[jb * 8 + 0].x = a0; h[jb * 8 + 0].y = b0v;
      h[jb * 8 + 1].x = a1; h[jb * 8 + 1].y = b1v;
      unpack2(vA.y, a0, a1); unpack2(vB.y, b0v, b1v);
      h[jb * 8 + 2].x = a0; h[jb * 8 + 2].y = b0v;
      h[jb * 8 + 3].x = a1; h[jb * 8 + 3].y = b1v;
      unpack2(vA.z, a0, a1); unpack2(vB.z, b0v, b1v);
      h[jb * 8 + 4].x = a0; h[jb * 8 + 4].y = b0v;
      h[jb * 8 + 5].x = a1; h[jb * 8 + 5].y = b1v;
      unpack2(vA.w, a0, a1); unpack2(vB.w, b0v, b1v);
      h[jb * 8 + 6].x = a0; h[jb * 8 + 6].y = b0v;
      h[jb * 8 + 7].x = a1; h[jb * 8 + 7].y = b1v;
    }
#pragma unroll
    for (int k = 0; k < 64; ++k)
      h[k] = vmax0(splat2(s3[k]) * h[k] + splat2(c3[k]));
    f32x2 t0 = dot64v(W4, h) + splat2(b4[0]);
    f32x2 t1 = dot64v(W4 + 64, h) + splat2(b4[1]);
    f32x2 t2 = dot64v(W4 + 128, h) + splat2(b4[2]);
    // row A
    {
      out[3 * r0 + 0] = t0.x;
      out[3 * r0 + 1] = t1.x;
      out[3 * r0 + 2] = t2.x;
      float s0, c0v, s1, c1v, s12, c12;
      sincosf(t0.x, &s0, &c0v);
      sincosf(t1.x, &s1, &c1v);
      sincosf(t1.x + t2.x, &s12, &c12);
      float A = fmaf(0.115f, c12, 0.12f * c1v);
      size_t o2 = (size_t)3 * B + 3 * r0;
      out[o2 + 0] = c0v * A;
      out[o2 + 1] = s0 * A;
      out[o2 + 2] = fmaf(0.115f, s12, 0.12f * s1);
    }
    if (r1 != r0) {
      out[3 * r1 + 0] = t0.y;
      out[3 * r1 + 1] = t1.y;
      out[3 * r1 + 2] = t2.y;
      float s0, c0v, s1, c1v, s12, c12;
      sincosf(t0.y, &s0, &c0v);
      sincosf(t1.y, &s1, &c1v);
      sincosf(t1.y + t2.y, &s12, &c12);
      float A = fmaf(0.115f, c12, 0.12f * c1v);
      size_t o2 = (size_t)3 * B + 3 * r1;
      out[o2 + 0] = c0v * A;
      out[o2 + 1] = s0 * A;
      out[o2 + 2] = fmaf(0.115f, s12, 0.12f * s1);
    }
  }
}

// ========================= FALLBACK (R1, verified) =========================

__device__ __forceinline__ void layer1_eval(const float* __restrict__ W1p,
                                            const float* __restrict__ c1,
                                            float x0, float x1, float x2,
                                            float h[64]) {
#pragma unroll
  for (int j = 0; j < 64; ++j) {
    float z = fmaf(W1p[3 * j + 2], x2,
               fmaf(W1p[3 * j + 1], x1, fmaf(W1p[3 * j], x0, c1[j])));
    h[j] = fmaxf(z, 0.f);
  }
}

__device__ __forceinline__ void dense_relu_rc(const float* __restrict__ Wp,
                                              const float* __restrict__ c,
                                              const float hin[64], float hout[64]) {
#pragma unroll
  for (int j = 0; j < 64; ++j)
    hout[j] = fmaxf(dot64(Wp + j * 64, hin) + c[j], 0.f);
}

__device__ __forceinline__ void dense_stats_rc(const float* __restrict__ W,
                                               const float* __restrict__ b,
                                               const float hin[64], int lane,
                                               float valid, float& accS, float& accQ) {
#pragma unroll 1
  for (int j = 0; j < 64; ++j) {
    float z = (dot64(W + j * 64, hin) + b[j]) * valid;
    float rs = wred64(z);
    float rq = wred64(z * z);
    accS += (lane == j) ? rs : 0.f;
    accQ += (lane == j) ? rq : 0.f;
  }
}

__device__ __forceinline__ void block_combine_rc(float accS, float accQ,
                                                 float* __restrict__ sumg,
                                                 float* __restrict__ ssqg) {
  __shared__ float sS[256], sQ[256];
  sS[threadIdx.x] = accS;
  sQ[threadIdx.x] = accQ;
  __syncthreads();
  if (threadIdx.x < 64) {
    float S = sS[threadIdx.x] + sS[threadIdx.x + 64] + sS[threadIdx.x + 128] + sS[threadIdx.x + 192];
    float Q = sQ[threadIdx.x] + sQ[threadIdx.x + 64] + sQ[threadIdx.x + 128] + sQ[threadIdx.x + 192];
    atomicAdd(&sumg[threadIdx.x], S);
    atomicAdd(&ssqg[threadIdx.x], Q);
  }
}

__global__ void __launch_bounds__(256) k_stats2_rc(const float* __restrict__ x,
                                                   const float* __restrict__ W2,
                                                   const float* __restrict__ b2,
                                                   float* __restrict__ ws, int B) {
  const float* W1p = ws + WS_W1P;
  const float* c1 = ws + WS_C1;
  int tid = blockIdx.x * 256 + threadIdx.x;
  int nt = gridDim.x * 256;
  int lane = threadIdx.x & 63;
  float accS = 0.f, accQ = 0.f;
  int iters = (B + nt - 1) / nt;
  for (int it = 0; it < iters; ++it) {
    int r = tid + it * nt;
    float valid = (r < B) ? 1.f : 0.f;
    int rc = (r < B) ? r : (B - 1);
    float h1[64];
    layer1_eval(W1p, c1, x[3 * rc], x[3 * rc + 1], x[3 * rc + 2], h1);
    dense_stats_rc(W2, b2, h1, lane, valid, accS, accQ);
  }
  block_combine_rc(accS, accQ, ws + WS_SUM2, ws + WS_SSQ2);
}

__global__ void k_fin_dense_rc(const float* __restrict__ W, const float* __restrict__ b,
                               const float* __restrict__ g, const float* __restrict__ be,
                               const float* __restrict__ sum, const float* __restrict__ ssq,
                               float* __restrict__ Wp, float* __restrict__ cc, int B) {
  int j = threadIdx.x;
  float inv = 1.0f / (float)B;
  float mean = sum[j] * inv;
  float var = ssq[j] * inv - mean * mean;
  float s = g[j] * rsqrtf(var + kEps);
  for (int k = 0; k < 64; ++k) Wp[j * 64 + k] = s * W[j * 64 + k];
  cc[j] = fmaf(s, b[j] - mean, be[j]);
}

__global__ void __launch_bounds__(256) k_stats3_rc(const float* __restrict__ x,
                                                   const float* __restrict__ W3,
                                                   const float* __restrict__ b3,
                                                   float* __restrict__ ws, int B) {
  const float* W1p = ws + WS_W1P;
  const float* c1 = ws + WS_C1;
  const float* W2p = ws + RC_W2P;
  const float* c2 = ws + RC_C2;
  int tid = blockIdx.x * 256 + threadIdx.x;
  int nt = gridDim.x * 256;
  int lane = threadIdx.x & 63;
  float accS = 0.f, accQ = 0.f;
  int iters = (B + nt - 1) / nt;
  for (int it = 0; it < iters; ++it) {
    int r = tid + it * nt;
    float valid = (r < B) ? 1.f : 0.f;
    int rc = (r < B) ? r : (B - 1);
    float h1[64], h2[64];
    layer1_eval(W1p, c1, x[3 * rc], x[3 * rc + 1], x[3 * rc + 2], h1);
    dense_relu_rc(W2p, c2, h1, h2);
    dense_stats_rc(W3, b3, h2, lane, valid, accS, accQ);
  }
  block_combine_rc(accS, accQ, ws + WS_SUM3, ws + WS_SSQ3);
}

__global__ void __launch_bounds__(256) k_final_rc(const float* __restrict__ x,
                                                  const float* __restrict__ W4,
                                                  const float* __restrict__ b4,
                                                  const float* __restrict__ ws,
                                                  float* __restrict__ out, int B) {
  const float* W1p = ws + WS_W1P;
  const float* c1 = ws + WS_C1;
  const float* W2p = ws + RC_W2P;
  const float* c2 = ws + RC_C2;
  const float* W3p = ws + RC_W3P;
  const float* c3 = ws + RC_C3;
  int tid = blockIdx.x * 256 + threadIdx.x;
  int nt = gridDim.x * 256;
  for (int r = tid; r < B; r += nt) {
    float h1[64], h2[64];
    layer1_eval(W1p, c1, x[3 * r], x[3 * r + 1], x[3 * r + 2], h1);
    dense_relu_rc(W2p, c2, h1, h2);
    float t0 = b4[0], t1 = b4[1], t2 = b4[2];
#pragma unroll 1
    for (int j = 0; j < 64; ++j) {
      float h3 = fmaxf(dot64(W3p + j * 64, h2) + c3[j], 0.f);
      t0 = fmaf(W4[j], h3, t0);
      t1 = fmaf(W4[64 + j], h3, t1);
      t2 = fmaf(W4[128 + j], h3, t2);
    }
    out[3 * r + 0] = t0;
    out[3 * r + 1] = t1;
    out[3 * r + 2] = t2;
    float s0, c0v, s1, c1v, s12, c12;
    sincosf(t0, &s0, &c0v);
    sincosf(t1, &s1, &c1v);
    sincosf(t1 + t2, &s12, &c12);
    float A = fmaf(0.115f, c12, 0.12f * c1v);
    size_t o2 = (size_t)3 * B + 3 * r;
    out[o2 + 0] = c0v * A;
    out[o2 + 1] = s0 * A;
    out[o2 + 2] = fmaf(0.115f, s12, 0.12f * s1);
  }
}

// ===========================================================================

extern "C" void kernel_launch(void* const* d_in, const int* in_sizes, int n_in,
                              void* d_out, int out_size, void* d_ws, size_t ws_size,
                              hipStream_t stream) {
  const float* x = (const float*)d_in[0];
  const float* W1 = (const float*)d_in[1];
  const float* b1 = (const float*)d_in[2];
  const float* g1 = (const float*)d_in[3];
  const float* be1 = (const float*)d_in[4];
  const float* W2 = (const float*)d_in[5];
  const float* b2 = (const float*)d_in[6];
  const float* g2 = (const float*)d_in[7];
  const float* be2 = (const float*)d_in[8];
  const float* W3 = (const float*)d_in[9];
  const float* b3 = (const float*)d_in[10];
  const float* g3 = (const float*)d_in[11];
  const float* be3 = (const float*)d_in[12];
  const float* W4 = (const float*)d_in[13];
  const float* b4 = (const float*)d_in[14];
  float* ws = (float*)d_ws;
  float* out = (float*)d_out;
  int B = in_sizes[0] / 3;

  hipMemsetAsync(d_ws, 0, 272 * sizeof(float), stream);

  const int blocks = 1024, thr = 256;
  const int zblocks = 2048;
  size_t need = 65536 + (size_t)B * 64 * 2;

  k_stats_x<<<blocks, thr, 0, stream>>>(x, ws, B);
  k_fin1<<<1, 64, 0, stream>>>(W1, b1, g1, be1, ws, B);

  if (ws_size >= need) {
    unsigned short* zb = (unsigned short*)ws + ZB_U16;
    k_z2<<<zblocks, thr, 0, stream>>>(x, W2, b2, ws, zb, B);
    k_colstats<<<blocks, thr, 0, stream>>>(zb, ws + WS_SUM2, ws + WS_SSQ2, B);
    k_fin_bn<<<1, 64, 0, stream>>>(ws + WS_SUM2, ws + WS_SSQ2, g2, be2,
                                   ws + FP_S2, ws + FP_C2, B);
    k_z3<<<zblocks, thr, 0, stream>>>(W3, b3, ws, zb, B);
    k_colstats<<<blocks, thr, 0, stream>>>(zb, ws + WS_SUM3, ws + WS_SSQ3, B);
    k_fin_bn<<<1, 64, 0, stream>>>(ws + WS_SUM3, ws + WS_SSQ3, g3, be3,
                                   ws + FP_S3, ws + FP_C3, B);
    k_final_fast<<<zblocks, thr, 0, stream>>>(zb, W4, b4, ws, out, B);
  } else {
    k_stats2_rc<<<blocks, thr, 0, stream>>>(x, W2, b2, ws, B);
    k_fin_dense_rc<<<1, 64, 0, stream>>>(W2, b2, g2, be2, ws + WS_SUM2, ws + WS_SSQ2,
                                         ws + RC_W2P, ws + RC_C2, B);
    k_stats3_rc<<<blocks, thr, 0, stream>>>(x, W3, b3, ws, B);
    k_fin_dense_rc<<<1, 64, 0, stream>>>(W3, b3, g3, be3, ws + WS_SUM3, ws + WS_SSQ3,
                                         ws + RC_W3P, ws + RC_C3, B);
    k_final_rc<<<blocks, thr, 0, stream>>>(x, W4, b4, ws, out, B);
  }
}

// Round 8
// 725.155 us; speedup vs baseline: 2.6528x; 1.0240x over previous
//
#include <hip/hip_runtime.h>
#include <math.h>

// ---------------------------------------------------------------------------
// InvKin, fp32-VALU pipeline with bf16 z-materialization (R7).
// R6: launch_bounds(256,2) fixed k_z3's spill but k_z2 still spills
// (VGPR=116, WRITE 604 MB vs 134 real). Root cause: the second launch_bounds
// arg only sets MIN waves/EU (a VGPR ceiling); the allocator's occupancy
// heuristic still targets ~4 waves/EU and spills h[64] to get there.
// R7: pin with amdgpu_waves_per_eu(2,2) (min=max) on the heavy kernels so
// the allocator plans for exactly 2 waves/EU (256-VGPR budget, no spill).
//   P1 k_stats_x : x second moments (layer-1 BN stats analytic)
//   P2 k_fin1    : fold BN1 -> fp32 W1p[64][3] + c1[64]
//   P3 k_z2      : h1 -> raw z2 -> bf16 zbuf[B][64]   (2 rows/thread, pk math)
//   P4 k_colstats: coalesced per-unit sum/ssq of zbuf
//   P5 k_fin_bn  : s2,c2
//   P6 k_z3      : h2 = relu(s2*z2+c2); z3 = W3 h2 + b3 in place
//   P7 k_colstats: stats of z3
//   P8 k_fin_bn  : s3,c3
//   P9 k_final   : h3 -> head -> closed-form FK -> out
// Fallback path (small ws): exact R1 kernel set (verified PASS).
// ---------------------------------------------------------------------------

static constexpr float kEps = 1e-5f;

typedef __attribute__((ext_vector_type(2))) float f32x2;

#define HEAVY_BOUNDS __launch_bounds__(256) __attribute__((amdgpu_waves_per_eu(2, 2)))

// shared ws fp32 indices (both paths)
#define WS_STAT9 0
#define WS_SUM2  16
#define WS_SSQ2  80
#define WS_SUM3  144
#define WS_SSQ3  208
#define WS_W1P   288    // [64][3] fp32 (BN1-folded)
#define WS_C1    480    // [64]
// fast path only
#define FP_S2    8192
#define FP_C2    8256
#define FP_S3    8320
#define FP_C3    8384
// fallback (R1) only — may overlap FP_* since only one path ever runs
#define RC_W2P   544
#define RC_C2    4640
#define RC_W3P   4704
#define RC_C3    8800
// z buffer: byte offset 65536 (ushort index 32768)
#define ZB_U16   32768

__device__ __forceinline__ unsigned short f2bf(float f) {
  unsigned u = __builtin_bit_cast(unsigned, f);
  u += 0x7fffu + ((u >> 16) & 1u);
  return (unsigned short)(u >> 16);
}
__device__ __forceinline__ unsigned packbf2(float a, float b) {
  return (unsigned)f2bf(a) | ((unsigned)f2bf(b) << 16);
}
__device__ __forceinline__ void unpack2(unsigned w, float& lo, float& hi) {
  lo = __builtin_bit_cast(float, w << 16);
  hi = __builtin_bit_cast(float, w & 0xffff0000u);
}
__device__ __forceinline__ float bfbits(unsigned short s) {
  unsigned u = ((unsigned)s) << 16;
  return __builtin_bit_cast(float, u);
}
__device__ __forceinline__ f32x2 splat2(float v) {
  f32x2 r; r.x = v; r.y = v; return r;
}
__device__ __forceinline__ f32x2 vmax0(f32x2 v) {
  f32x2 r; r.x = fmaxf(v.x, 0.f); r.y = fmaxf(v.y, 0.f); return r;
}

__device__ __forceinline__ float wred64(float v) {
  v += __shfl_xor(v, 32, 64);
  v += __shfl_xor(v, 16, 64);
  v += __shfl_xor(v, 8, 64);
  v += __shfl_xor(v, 4, 64);
  v += __shfl_xor(v, 2, 64);
  v += __shfl_xor(v, 1, 64);
  return v;
}

// packed dual-row dot: (zA,zB) = sum_k w[k] * (hA[k],hB[k])
__device__ __forceinline__ f32x2 dot64v(const float* __restrict__ wr,
                                        const f32x2* __restrict__ h) {
  f32x2 a0 = splat2(0.f), a1 = splat2(0.f), a2 = splat2(0.f), a3 = splat2(0.f);
#pragma unroll
  for (int k = 0; k < 64; k += 4) {
    a0 += splat2(wr[k + 0]) * h[k + 0];
    a1 += splat2(wr[k + 1]) * h[k + 1];
    a2 += splat2(wr[k + 2]) * h[k + 2];
    a3 += splat2(wr[k + 3]) * h[k + 3];
  }
  return (a0 + a1) + (a2 + a3);
}

__device__ __forceinline__ float dot64(const float* __restrict__ wr,
                                       const float hin[64]) {
  float a0 = 0.f, a1 = 0.f, a2 = 0.f, a3 = 0.f;
#pragma unroll
  for (int k = 0; k < 64; k += 4) {
    a0 = fmaf(wr[k + 0], hin[k + 0], a0);
    a1 = fmaf(wr[k + 1], hin[k + 1], a1);
    a2 = fmaf(wr[k + 2], hin[k + 2], a2);
    a3 = fmaf(wr[k + 3], hin[k + 3], a3);
  }
  return (a0 + a1) + (a2 + a3);
}

// ---- P1: x second moments (shared) ---------------------------------------
__global__ void __launch_bounds__(256) k_stats_x(const float* __restrict__ x,
                                                 float* __restrict__ ws, int B) {
  int tid = blockIdx.x * 256 + threadIdx.x;
  int nt = gridDim.x * 256;
  float s0 = 0.f, s1 = 0.f, s2 = 0.f;
  float q00 = 0.f, q01 = 0.f, q02 = 0.f, q11 = 0.f, q12 = 0.f, q22 = 0.f;
  for (int r = tid; r < B; r += nt) {
    float x0 = x[3 * r], x1 = x[3 * r + 1], x2 = x[3 * r + 2];
    s0 += x0; s1 += x1; s2 += x2;
    q00 = fmaf(x0, x0, q00); q01 = fmaf(x0, x1, q01); q02 = fmaf(x0, x2, q02);
    q11 = fmaf(x1, x1, q11); q12 = fmaf(x1, x2, q12); q22 = fmaf(x2, x2, q22);
  }
  s0 = wred64(s0); s1 = wred64(s1); s2 = wred64(s2);
  q00 = wred64(q00); q01 = wred64(q01); q02 = wred64(q02);
  q11 = wred64(q11); q12 = wred64(q12); q22 = wred64(q22);
  __shared__ float part[9];
  if (threadIdx.x < 9) part[threadIdx.x] = 0.f;
  __syncthreads();
  if ((threadIdx.x & 63) == 0) {
    atomicAdd(&part[0], s0); atomicAdd(&part[1], s1); atomicAdd(&part[2], s2);
    atomicAdd(&part[3], q00); atomicAdd(&part[4], q01); atomicAdd(&part[5], q02);
    atomicAdd(&part[6], q11); atomicAdd(&part[7], q12); atomicAdd(&part[8], q22);
  }
  __syncthreads();
  if (threadIdx.x < 9) atomicAdd(&ws[WS_STAT9 + threadIdx.x], part[threadIdx.x]);
}

// ---- P2: fold BN1 (shared) ------------------------------------------------
__global__ void k_fin1(const float* __restrict__ W1, const float* __restrict__ b1,
                       const float* __restrict__ g1, const float* __restrict__ be1,
                       float* __restrict__ ws, int B) {
  int j = threadIdx.x;  // 64
  float inv = 1.0f / (float)B;
  float ex0 = ws[0] * inv, ex1 = ws[1] * inv, ex2 = ws[2] * inv;
  float c00 = ws[3] * inv - ex0 * ex0;
  float c01 = ws[4] * inv - ex0 * ex1;
  float c02 = ws[5] * inv - ex0 * ex2;
  float c11 = ws[6] * inv - ex1 * ex1;
  float c12 = ws[7] * inv - ex1 * ex2;
  float c22 = ws[8] * inv - ex2 * ex2;
  float w0 = W1[3 * j], w1 = W1[3 * j + 1], w2 = W1[3 * j + 2];
  float mean = w0 * ex0 + w1 * ex1 + w2 * ex2 + b1[j];
  float var = w0 * w0 * c00 + w1 * w1 * c11 + w2 * w2 * c22 +
              2.f * (w0 * w1 * c01 + w0 * w2 * c02 + w1 * w2 * c12);
  float s = g1[j] * rsqrtf(var + kEps);
  ws[WS_W1P + 3 * j + 0] = s * w0;
  ws[WS_W1P + 3 * j + 1] = s * w1;
  ws[WS_W1P + 3 * j + 2] = s * w2;
  ws[WS_C1 + j] = fmaf(s, b1[j] - mean, be1[j]);
}

// =========================== FAST PATH =====================================

// ---- P3: z2 = W2 h1 + b2 -> bf16 zbuf (2 rows/thread, packed) ------------
__global__ void HEAVY_BOUNDS k_z2(const float* __restrict__ x,
                                  const float* __restrict__ W2,
                                  const float* __restrict__ b2,
                                  const float* __restrict__ ws,
                                  unsigned short* __restrict__ zb, int B) {
  const float* W1p = ws + WS_W1P;
  const float* c1 = ws + WS_C1;
  int tid = blockIdx.x * 256 + threadIdx.x;
  int nt = gridDim.x * 256;
  int npair = (B + 1) >> 1;
  for (int p = tid; p < npair; p += nt) {
    int r0 = 2 * p;
    int r1 = (r0 + 1 < B) ? (r0 + 1) : r0;
    f32x2 xv0, xv1, xv2;
    xv0.x = x[3 * r0];     xv0.y = x[3 * r1];
    xv1.x = x[3 * r0 + 1]; xv1.y = x[3 * r1 + 1];
    xv2.x = x[3 * r0 + 2]; xv2.y = x[3 * r1 + 2];
    f32x2 h[64];
#pragma unroll
    for (int k = 0; k < 64; ++k) {
      f32x2 z = splat2(c1[k]);
      z += splat2(W1p[3 * k + 0]) * xv0;
      z += splat2(W1p[3 * k + 1]) * xv1;
      z += splat2(W1p[3 * k + 2]) * xv2;
      h[k] = vmax0(z);
    }
    uint4* zrA = (uint4*)(zb + (size_t)r0 * 64);
    uint4* zrB = (uint4*)(zb + (size_t)r1 * 64);
#pragma unroll 1
    for (int jb = 0; jb < 8; ++jb) {
      f32x2 z[8];
#pragma unroll
      for (int u = 0; u < 8; ++u) {
        int j = jb * 8 + u;
        z[u] = dot64v(W2 + j * 64, h) + splat2(b2[j]);
      }
      uint4 oA, oB;
      oA.x = packbf2(z[0].x, z[1].x); oA.y = packbf2(z[2].x, z[3].x);
      oA.z = packbf2(z[4].x, z[5].x); oA.w = packbf2(z[6].x, z[7].x);
      oB.x = packbf2(z[0].y, z[1].y); oB.y = packbf2(z[2].y, z[3].y);
      oB.z = packbf2(z[4].y, z[5].y); oB.w = packbf2(z[6].y, z[7].y);
      zrA[jb] = oA;
      zrB[jb] = oB;
    }
  }
}

// ---- P4/P7: coalesced per-unit sum/ssq of zbuf ---------------------------
__global__ void __launch_bounds__(256) k_colstats(const unsigned short* __restrict__ zb,
                                                  float* __restrict__ sumg,
                                                  float* __restrict__ ssqg, int B) {
  int u = threadIdx.x & 63;
  int rloc = threadIdx.x >> 6;              // 0..3
  int rstep = gridDim.x * 4;
  float accS = 0.f, accQ = 0.f;
  for (int r = blockIdx.x * 4 + rloc; r < B; r += rstep) {
    float z = bfbits(zb[(size_t)r * 64 + u]);
    accS += z;
    accQ = fmaf(z, z, accQ);
  }
  __shared__ float sS[64], sQ[64];
  if (threadIdx.x < 64) { sS[threadIdx.x] = 0.f; sQ[threadIdx.x] = 0.f; }
  __syncthreads();
  atomicAdd(&sS[u], accS);
  atomicAdd(&sQ[u], accQ);
  __syncthreads();
  if (threadIdx.x < 64) {
    atomicAdd(&sumg[threadIdx.x], sS[threadIdx.x]);
    atomicAdd(&ssqg[threadIdx.x], sQ[threadIdx.x]);
  }
}

// ---- P5/P8: BN scale/shift only ------------------------------------------
__global__ void k_fin_bn(const float* __restrict__ sum, const float* __restrict__ ssq,
                         const float* __restrict__ g, const float* __restrict__ be,
                         float* __restrict__ sOut, float* __restrict__ cOut, int B) {
  int j = threadIdx.x;  // 64
  float inv = 1.0f / (float)B;
  float mean = sum[j] * inv;
  float var = ssq[j] * inv - mean * mean;
  float s = g[j] * rsqrtf(var + kEps);
  sOut[j] = s;
  cOut[j] = fmaf(-s, mean, be[j]);
}

// ---- P6: z3 = W3 relu(s2*z2+c2) + b3, in place (2 rows/thread) -----------
__global__ void HEAVY_BOUNDS k_z3(const float* __restrict__ W3,
                                  const float* __restrict__ b3,
                                  const float* __restrict__ ws,
                                  unsigned short* __restrict__ zb, int B) {
  const float* s2 = ws + FP_S2;
  const float* c2 = ws + FP_C2;
  int tid = blockIdx.x * 256 + threadIdx.x;
  int nt = gridDim.x * 256;
  int npair = (B + 1) >> 1;
  for (int p = tid; p < npair; p += nt) {
    int r0 = 2 * p;
    int r1 = (r0 + 1 < B) ? (r0 + 1) : r0;
    uint4* zrA = (uint4*)(zb + (size_t)r0 * 64);
    uint4* zrB = (uint4*)(zb + (size_t)r1 * 64);
    f32x2 h[64];
#pragma unroll
    for (int jb = 0; jb < 8; ++jb) {
      uint4 vA = zrA[jb], vB = zrB[jb];
      float a0, a1, b0v, b1v;
      unpack2(vA.x, a0, a1); unpack2(vB.x, b0v, b1v);
      h[jb * 8 + 0].x = a0; h[jb * 8 + 0].y = b0v;
      h[jb * 8 + 1].x = a1; h[jb * 8 + 1].y = b1v;
      unpack2(vA.y, a0, a1); unpack2(vB.y, b0v, b1v);
      h[jb * 8 + 2].x = a0; h[jb * 8 + 2].y = b0v;
      h[jb * 8 + 3].x = a1; h[jb * 8 + 3].y = b1v;
      unpack2(vA.z, a0, a1); unpack2(vB.z, b0v, b1v);
      h[jb * 8 + 4].x = a0; h[jb * 8 + 4].y = b0v;
      h[jb * 8 + 5].x = a1; h[jb * 8 + 5].y = b1v;
      unpack2(vA.w, a0, a1); unpack2(vB.w, b0v, b1v);
      h[jb * 8 + 6].x = a0; h[jb * 8 + 6].y = b0v;
      h[jb * 8 + 7].x = a1; h[jb * 8 + 7].y = b1v;
    }
#pragma unroll
    for (int k = 0; k < 64; ++k)
      h[k] = vmax0(splat2(s2[k]) * h[k] + splat2(c2[k]));
#pragma unroll 1
    for (int jb = 0; jb < 8; ++jb) {
      f32x2 z[8];
#pragma unroll
      for (int u = 0; u < 8; ++u) {
        int j = jb * 8 + u;
        z[u] = dot64v(W3 + j * 64, h) + splat2(b3[j]);
      }
      uint4 oA, oB;
      oA.x = packbf2(z[0].x, z[1].x); oA.y = packbf2(z[2].x, z[3].x);
      oA.z = packbf2(z[4].x, z[5].x); oA.w = packbf2(z[6].x, z[7].x);
      oB.x = packbf2(z[0].y, z[1].y); oB.y = packbf2(z[2].y, z[3].y);
      oB.z = packbf2(z[4].y, z[5].y); oB.w = packbf2(z[6].y, z[7].y);
      zrA[jb] = oA;
      zrB[jb] = oB;
    }
  }
}

// ---- P9: h3 -> head -> FK -> out (2 rows/thread) --------------------------
__global__ void HEAVY_BOUNDS k_final_fast(const unsigned short* __restrict__ zb,
                                          const float* __restrict__ W4,
                                          const float* __restrict__ b4,
                                          const float* __restrict__ ws,
                                          float* __restrict__ out, int B) {
  const float* s3 = ws + FP_S3;
  const float* c3 = ws + FP_C3;
  int tid = blockIdx.x * 256 + threadIdx.x;
  int nt = gridDim.x * 256;
  int npair = (B + 1) >> 1;
  for (int p = tid; p < npair; p += nt) {
    int r0 = 2 * p;
    int r1 = (r0 + 1 < B) ? (r0 + 1) : r0;
    const uint4* zrA = (const uint4*)(zb + (size_t)r0 * 64);
    const uint4* zrB = (const uint4*)(zb + (size_t)r1 * 64);
    f32x2 h[64];
#pragma unroll
    for (int jb = 0; jb < 8; ++jb) {
      uint4 vA = zrA[jb], vB = zrB[jb];
      float a0, a1, b0v, b1v;
      unpack2(vA.x, a0, a1); unpack2(vB.x, b0v, b1v);
      h[jb * 8 + 0].x = a0; h[jb * 8 + 0].y = b0v;
      h[jb * 8 + 1].x = a1; h[jb * 8 + 1].y = b1v;
      unpack2(vA.y, a0, a1); unpack2(vB.y, b0v, b1v);
      h[jb * 8 + 2].x = a0; h[jb * 8 + 2].y = b0v;
      h[jb * 8 + 3].x = a1; h[jb * 8 + 3].y = b1v;
      unpack2(vA.z, a0, a1); unpack2(vB.z, b0v, b1v);
      h[jb * 8 + 4].x = a0; h[jb * 8 + 4].y = b0v;
      h[jb * 8 + 5].x = a1; h[jb * 8 + 5].y = b1v;
      unpack2(vA.w, a0, a1); unpack2(vB.w, b0v, b1v);
      h[jb * 8 + 6].x = a0; h[jb * 8 + 6].y = b0v;
      h[jb * 8 + 7].x = a1; h[jb * 8 + 7].y = b1v;
    }
#pragma unroll
    for (int k = 0; k < 64; ++k)
      h[k] = vmax0(splat2(s3[k]) * h[k] + splat2(c3[k]));
    f32x2 t0 = dot64v(W4, h) + splat2(b4[0]);
    f32x2 t1 = dot64v(W4 + 64, h) + splat2(b4[1]);
    f32x2 t2 = dot64v(W4 + 128, h) + splat2(b4[2]);
    // row A
    {
      out[3 * r0 + 0] = t0.x;
      out[3 * r0 + 1] = t1.x;
      out[3 * r0 + 2] = t2.x;
      float s0, c0v, s1, c1v, s12, c12;
      sincosf(t0.x, &s0, &c0v);
      sincosf(t1.x, &s1, &c1v);
      sincosf(t1.x + t2.x, &s12, &c12);
      float A = fmaf(0.115f, c12, 0.12f * c1v);
      size_t o2 = (size_t)3 * B + 3 * r0;
      out[o2 + 0] = c0v * A;
      out[o2 + 1] = s0 * A;
      out[o2 + 2] = fmaf(0.115f, s12, 0.12f * s1);
    }
    if (r1 != r0) {
      out[3 * r1 + 0] = t0.y;
      out[3 * r1 + 1] = t1.y;
      out[3 * r1 + 2] = t2.y;
      float s0, c0v, s1, c1v, s12, c12;
      sincosf(t0.y, &s0, &c0v);
      sincosf(t1.y, &s1, &c1v);
      sincosf(t1.y + t2.y, &s12, &c12);
      float A = fmaf(0.115f, c12, 0.12f * c1v);
      size_t o2 = (size_t)3 * B + 3 * r1;
      out[o2 + 0] = c0v * A;
      out[o2 + 1] = s0 * A;
      out[o2 + 2] = fmaf(0.115f, s12, 0.12f * s1);
    }
  }
}

// ========================= FALLBACK (R1, verified) =========================

__device__ __forceinline__ void layer1_eval(const float* __restrict__ W1p,
                                            const float* __restrict__ c1,
                                            float x0, float x1, float x2,
                                            float h[64]) {
#pragma unroll
  for (int j = 0; j < 64; ++j) {
    float z = fmaf(W1p[3 * j + 2], x2,
               fmaf(W1p[3 * j + 1], x1, fmaf(W1p[3 * j], x0, c1[j])));
    h[j] = fmaxf(z, 0.f);
  }
}

__device__ __forceinline__ void dense_relu_rc(const float* __restrict__ Wp,
                                              const float* __restrict__ c,
                                              const float hin[64], float hout[64]) {
#pragma unroll
  for (int j = 0; j < 64; ++j)
    hout[j] = fmaxf(dot64(Wp + j * 64, hin) + c[j], 0.f);
}

__device__ __forceinline__ void dense_stats_rc(const float* __restrict__ W,
                                               const float* __restrict__ b,
                                               const float hin[64], int lane,
                                               float valid, float& accS, float& accQ) {
#pragma unroll 1
  for (int j = 0; j < 64; ++j) {
    float z = (dot64(W + j * 64, hin) + b[j]) * valid;
    float rs = wred64(z);
    float rq = wred64(z * z);
    accS += (lane == j) ? rs : 0.f;
    accQ += (lane == j) ? rq : 0.f;
  }
}

__device__ __forceinline__ void block_combine_rc(float accS, float accQ,
                                                 float* __restrict__ sumg,
                                                 float* __restrict__ ssqg) {
  __shared__ float sS[256], sQ[256];
  sS[threadIdx.x] = accS;
  sQ[threadIdx.x] = accQ;
  __syncthreads();
  if (threadIdx.x < 64) {
    float S = sS[threadIdx.x] + sS[threadIdx.x + 64] + sS[threadIdx.x + 128] + sS[threadIdx.x + 192];
    float Q = sQ[threadIdx.x] + sQ[threadIdx.x + 64] + sQ[threadIdx.x + 128] + sQ[threadIdx.x + 192];
    atomicAdd(&sumg[threadIdx.x], S);
    atomicAdd(&ssqg[threadIdx.x], Q);
  }
}

__global__ void __launch_bounds__(256) k_stats2_rc(const float* __restrict__ x,
                                                   const float* __restrict__ W2,
                                                   const float* __restrict__ b2,
                                                   float* __restrict__ ws, int B) {
  const float* W1p = ws + WS_W1P;
  const float* c1 = ws + WS_C1;
  int tid = blockIdx.x * 256 + threadIdx.x;
  int nt = gridDim.x * 256;
  int lane = threadIdx.x & 63;
  float accS = 0.f, accQ = 0.f;
  int iters = (B + nt - 1) / nt;
  for (int it = 0; it < iters; ++it) {
    int r = tid + it * nt;
    float valid = (r < B) ? 1.f : 0.f;
    int rc = (r < B) ? r : (B - 1);
    float h1[64];
    layer1_eval(W1p, c1, x[3 * rc], x[3 * rc + 1], x[3 * rc + 2], h1);
    dense_stats_rc(W2, b2, h1, lane, valid, accS, accQ);
  }
  block_combine_rc(accS, accQ, ws + WS_SUM2, ws + WS_SSQ2);
}

__global__ void k_fin_dense_rc(const float* __restrict__ W, const float* __restrict__ b,
                               const float* __restrict__ g, const float* __restrict__ be,
                               const float* __restrict__ sum, const float* __restrict__ ssq,
                               float* __restrict__ Wp, float* __restrict__ cc, int B) {
  int j = threadIdx.x;
  float inv = 1.0f / (float)B;
  float mean = sum[j] * inv;
  float var = ssq[j] * inv - mean * mean;
  float s = g[j] * rsqrtf(var + kEps);
  for (int k = 0; k < 64; ++k) Wp[j * 64 + k] = s * W[j * 64 + k];
  cc[j] = fmaf(s, b[j] - mean, be[j]);
}

__global__ void __launch_bounds__(256) k_stats3_rc(const float* __restrict__ x,
                                                   const float* __restrict__ W3,
                                                   const float* __restrict__ b3,
                                                   float* __restrict__ ws, int B) {
  const float* W1p = ws + WS_W1P;
  const float* c1 = ws + WS_C1;
  const float* W2p = ws + RC_W2P;
  const float* c2 = ws + RC_C2;
  int tid = blockIdx.x * 256 + threadIdx.x;
  int nt = gridDim.x * 256;
  int lane = threadIdx.x & 63;
  float accS = 0.f, accQ = 0.f;
  int iters = (B + nt - 1) / nt;
  for (int it = 0; it < iters; ++it) {
    int r = tid + it * nt;
    float valid = (r < B) ? 1.f : 0.f;
    int rc = (r < B) ? r : (B - 1);
    float h1[64], h2[64];
    layer1_eval(W1p, c1, x[3 * rc], x[3 * rc + 1], x[3 * rc + 2], h1);
    dense_relu_rc(W2p, c2, h1, h2);
    dense_stats_rc(W3, b3, h2, lane, valid, accS, accQ);
  }
  block_combine_rc(accS, accQ, ws + WS_SUM3, ws + WS_SSQ3);
}

__global__ void __launch_bounds__(256) k_final_rc(const float* __restrict__ x,
                                                  const float* __restrict__ W4,
                                                  const float* __restrict__ b4,
                                                  const float* __restrict__ ws,
                                                  float* __restrict__ out, int B) {
  const float* W1p = ws + WS_W1P;
  const float* c1 = ws + WS_C1;
  const float* W2p = ws + RC_W2P;
  const float* c2 = ws + RC_C2;
  const float* W3p = ws + RC_W3P;
  const float* c3 = ws + RC_C3;
  int tid = blockIdx.x * 256 + threadIdx.x;
  int nt = gridDim.x * 256;
  for (int r = tid; r < B; r += nt) {
    float h1[64], h2[64];
    layer1_eval(W1p, c1, x[3 * r], x[3 * r + 1], x[3 * r + 2], h1);
    dense_relu_rc(W2p, c2, h1, h2);
    float t0 = b4[0], t1 = b4[1], t2 = b4[2];
#pragma unroll 1
    for (int j = 0; j < 64; ++j) {
      float h3 = fmaxf(dot64(W3p + j * 64, h2) + c3[j], 0.f);
      t0 = fmaf(W4[j], h3, t0);
      t1 = fmaf(W4[64 + j], h3, t1);
      t2 = fmaf(W4[128 + j], h3, t2);
    }
    out[3 * r + 0] = t0;
    out[3 * r + 1] = t1;
    out[3 * r + 2] = t2;
    float s0, c0v, s1, c1v, s12, c12;
    sincosf(t0, &s0, &c0v);
    sincosf(t1, &s1, &c1v);
    sincosf(t1 + t2, &s12, &c12);
    float A = fmaf(0.115f, c12, 0.12f * c1v);
    size_t o2 = (size_t)3 * B + 3 * r;
    out[o2 + 0] = c0v * A;
    out[o2 + 1] = s0 * A;
    out[o2 + 2] = fmaf(0.115f, s12, 0.12f * s1);
  }
}

// ===========================================================================

extern "C" void kernel_launch(void* const* d_in, const int* in_sizes, int n_in,
                              void* d_out, int out_size, void* d_ws, size_t ws_size,
                              hipStream_t stream) {
  const float* x = (const float*)d_in[0];
  const float* W1 = (const float*)d_in[1];
  const float* b1 = (const float*)d_in[2];
  const float* g1 = (const float*)d_in[3];
  const float* be1 = (const float*)d_in[4];
  const float* W2 = (const float*)d_in[5];
  const float* b2 = (const float*)d_in[6];
  const float* g2 = (const float*)d_in[7];
  const float* be2 = (const float*)d_in[8];
  const float* W3 = (const float*)d_in[9];
  const float* b3 = (const float*)d_in[10];
  const float* g3 = (const float*)d_in[11];
  const float* be3 = (const float*)d_in[12];
  const float* W4 = (const float*)d_in[13];
  const float* b4 = (const float*)d_in[14];
  float* ws = (float*)d_ws;
  float* out = (float*)d_out;
  int B = in_sizes[0] / 3;

  hipMemsetAsync(d_ws, 0, 272 * sizeof(float), stream);

  const int blocks = 1024, thr = 256;
  const int zblocks = 2048;
  size_t need = 65536 + (size_t)B * 64 * 2;

  k_stats_x<<<blocks, thr, 0, stream>>>(x, ws, B);
  k_fin1<<<1, 64, 0, stream>>>(W1, b1, g1, be1, ws, B);

  if (ws_size >= need) {
    unsigned short* zb = (unsigned short*)ws + ZB_U16;
    k_z2<<<zblocks, thr, 0, stream>>>(x, W2, b2, ws, zb, B);
    k_colstats<<<blocks, thr, 0, stream>>>(zb, ws + WS_SUM2, ws + WS_SSQ2, B);
    k_fin_bn<<<1, 64, 0, stream>>>(ws + WS_SUM2, ws + WS_SSQ2, g2, be2,
                                   ws + FP_S2, ws + FP_C2, B);
    k_z3<<<zblocks, thr, 0, stream>>>(W3, b3, ws, zb, B);
    k_colstats<<<blocks, thr, 0, stream>>>(zb, ws + WS_SUM3, ws + WS_SSQ3, B);
    k_fin_bn<<<1, 64, 0, stream>>>(ws + WS_SUM3, ws + WS_SSQ3, g3, be3,
                                   ws + FP_S3, ws + FP_C3, B);
    k_final_fast<<<zblocks, thr, 0, stream>>>(zb, W4, b4, ws, out, B);
  } else {
    k_stats2_rc<<<blocks, thr, 0, stream>>>(x, W2, b2, ws, B);
    k_fin_dense_rc<<<1, 64, 0, stream>>>(W2, b2, g2, be2, ws + WS_SUM2, ws + WS_SSQ2,
                                         ws + RC_W2P, ws + RC_C2, B);
    k_stats3_rc<<<blocks, thr, 0, stream>>>(x, W3, b3, ws, B);
    k_fin_dense_rc<<<1, 64, 0, stream>>>(W3, b3, g3, be3, ws + WS_SUM3, ws + WS_SSQ3,
                                         ws + RC_W3P, ws + RC_C3, B);
    k_final_rc<<<blocks, thr, 0, stream>>>(x, W4, b4, ws, out, B);
  }
}